// Round 6
// baseline (41547.806 us; speedup 1.0000x reference)
//
#include <hip/hip_runtime.h>
#include <cstdint>
#include <cstddef>

#define GXd 480
#define GYd 360
#define NBd 2
#define GXY (480*360)
#define NCELL (NBd*GXY)
#define EPSBN 1e-5f

// ---------- order-preserving float <-> uint map (residual atomics only) ----------
__device__ __forceinline__ unsigned mapf(float f){
    unsigned u = __float_as_uint(f);
    return (u & 0x80000000u) ? ~u : (u | 0x80000000u);
}
__device__ __forceinline__ float unmapf(unsigned m){
    return (m & 0x80000000u) ? __uint_as_float(m ^ 0x80000000u)
                             : __uint_as_float(~m);
}

// ---------- bf16 helpers (RTN-even) ----------
__device__ __forceinline__ unsigned short f2bf(float f){
    unsigned u = __float_as_uint(f);
    unsigned r = (u + 0x7FFFu + ((u >> 16) & 1u)) >> 16;
    return (unsigned short)r;
}
__device__ __forceinline__ float bf2f(unsigned short s){
    return __uint_as_float(((unsigned)s) << 16);
}

// ---------- dense layer helper ----------
template<int DIN, int DOUT>
__device__ __forceinline__ void dense(const float (&in)[DIN], float (&out)[DOUT],
                                      const float* __restrict__ w,
                                      const float* __restrict__ b){
#pragma unroll
    for (int j = 0; j < DOUT; j++) out[j] = b[j];
#pragma unroll
    for (int d = 0; d < DIN; d++){
        float v = in[d];
#pragma unroll
        for (int j = 0; j < DOUT; j++) out[j] = fmaf(v, w[d*DOUT + j], out[j]);
    }
}

// ---------- block-level sum/sumsq reduction ----------
template<int D>
__device__ __forceinline__ void reduce_stats(const float (&h)[D], bool valid,
                                             float* __restrict__ gsum,
                                             float* __restrict__ gsq){
    __shared__ float ssum[D];
    __shared__ float ssq[D];
    int tid = threadIdx.x;
    for (int t = tid; t < D; t += 256){ ssum[t] = 0.f; ssq[t] = 0.f; }
    __syncthreads();
#pragma unroll
    for (int j = 0; j < D; j++){
        float v = valid ? h[j] : 0.f;
        float s = v * v;
#pragma unroll
        for (int o = 32; o > 0; o >>= 1){
            v += __shfl_down(v, o, 64);
            s += __shfl_down(s, o, 64);
        }
        if ((tid & 63) == 0){
            atomicAdd(&ssum[j], v);
            atomicAdd(&ssq[j], s);
        }
    }
    __syncthreads();
    for (int t = tid; t < D; t += 256){
        atomicAdd(&gsum[t], ssum[t]);
        atomicAdd(&gsq[t], ssq[t]);
    }
}

// ---------- stats of raw input columns 0..8 ----------
__global__ __launch_bounds__(256)
void k_stats0(const float* __restrict__ fea, float* gsum, float* gsq, int n){
    int i = blockIdx.x*256 + threadIdx.x;
    bool valid = i < n;
    int i2 = valid ? i : 0;
    float x[9];
#pragma unroll
    for (int d = 0; d < 9; d++) x[d] = fea[(size_t)i2*11 + d];
    reduce_stats<9>(x, valid, gsum, gsq);
}

// ---------- finalize BN ----------
__global__ void k_fin(const float* __restrict__ sum, const float* __restrict__ sq,
                      const float* __restrict__ g, const float* __restrict__ bb,
                      float* __restrict__ a_out, float* __restrict__ c_out,
                      int D, float invN){
    int t = threadIdx.x;
    if (t < D){
        float mu  = sum[t] * invN;
        float var = fmaf(-mu, mu, sq[t] * invN);
        float rs  = rsqrtf(var + EPSBN);
        float a   = rs * g[t];
        a_out[t] = a;
        c_out[t] = fmaf(-mu, a, bb[t]);
    }
}

// ---------- layer1: bn0 -> 9x32; z1; stats; voxel count+rank; res atomics ----------
__global__ __launch_bounds__(256)
void k_l1(const float* __restrict__ fea, const int* __restrict__ ind,
          const float* __restrict__ w1, const float* __restrict__ b1,
          const float* __restrict__ a0, const float* __restrict__ c0,
          float* __restrict__ z1, unsigned* __restrict__ pres,
          unsigned* __restrict__ cnt, unsigned* __restrict__ rank,
          float* gsum, float* gsq, int n){
    int i = blockIdx.x*256 + threadIdx.x;
    bool valid = i < n;
    int i2 = valid ? i : 0;
    float x[9];
#pragma unroll
    for (int d = 0; d < 9; d++) x[d] = fmaf(fea[(size_t)i2*11 + d], a0[d], c0[d]);
    float h[32];
    dense<9,32>(x, h, w1, b1);
    if (valid){
        float4* dst = (float4*)(z1 + (size_t)i*32);
#pragma unroll
        for (int q = 0; q < 8; q++)
            dst[q] = make_float4(h[q*4], h[q*4+1], h[q*4+2], h[q*4+3]);
        float r0 = fea[(size_t)i*11 + 9];
        float r1 = fea[(size_t)i*11 + 10];
        int bb = ind[(size_t)i*3 + 0];
        int gx = ind[(size_t)i*3 + 1];
        int gy = ind[(size_t)i*3 + 2];
        unsigned vox = ((unsigned)bb*GXd + (unsigned)gx)*GYd + (unsigned)gy;
        rank[i] = atomicAdd(&cnt[vox], 1u);
        size_t rbase = (size_t)bb*2*GXY + (size_t)gx*GYd + gy;
        atomicMax(pres + rbase,       mapf(r0));
        atomicMax(pres + rbase + GXY, mapf(r1));
    }
    reduce_stats<32>(h, valid, gsum, gsq);
}

// ---------- layer2 ----------
__global__ __launch_bounds__(256)
void k_l2(const float* __restrict__ z1,
          const float* __restrict__ w2, const float* __restrict__ b2,
          const float* __restrict__ a1, const float* __restrict__ c1,
          float* __restrict__ z2, float* gsum, float* gsq, int n){
    __shared__ float4 w2s[32*16];
    for (int e = threadIdx.x; e < 2048; e += 256) ((float*)w2s)[e] = w2[e];
    __syncthreads();
    int i = blockIdx.x*256 + threadIdx.x;
    bool valid = i < n;
    int i2 = valid ? i : 0;
    float h[32];
    const float4* src = (const float4*)(z1 + (size_t)i2*32);
#pragma unroll
    for (int q = 0; q < 8; q++){
        float4 v = src[q];
        h[q*4+0] = fmaxf(fmaf(v.x, a1[q*4+0], c1[q*4+0]), 0.f);
        h[q*4+1] = fmaxf(fmaf(v.y, a1[q*4+1], c1[q*4+1]), 0.f);
        h[q*4+2] = fmaxf(fmaf(v.z, a1[q*4+2], c1[q*4+2]), 0.f);
        h[q*4+3] = fmaxf(fmaf(v.w, a1[q*4+3], c1[q*4+3]), 0.f);
    }
    float acc[64];
#pragma unroll
    for (int j = 0; j < 64; j++) acc[j] = b2[j];
#pragma unroll
    for (int k = 0; k < 32; k++){
        float v = h[k];
#pragma unroll
        for (int q = 0; q < 16; q++){
            float4 w = w2s[k*16 + q];
            acc[q*4+0] = fmaf(v, w.x, acc[q*4+0]);
            acc[q*4+1] = fmaf(v, w.y, acc[q*4+1]);
            acc[q*4+2] = fmaf(v, w.z, acc[q*4+2]);
            acc[q*4+3] = fmaf(v, w.w, acc[q*4+3]);
        }
    }
    if (valid){
        float4* dst = (float4*)(z2 + (size_t)i*64);
#pragma unroll
        for (int q = 0; q < 16; q++)
            dst[q] = make_float4(acc[q*4], acc[q*4+1], acc[q*4+2], acc[q*4+3]);
    }
    reduce_stats<64>(acc, valid, gsum, gsq);
}

// ---------- layer3: z3 bf16; stats from rounded values; cb loop PINNED (no unroll) ----------
__global__ __launch_bounds__(256)
void k_l3(const float* __restrict__ z2,
          const float* __restrict__ w3, const float* __restrict__ b3,
          const float* __restrict__ a2, const float* __restrict__ c2,
          unsigned short* __restrict__ z3, float* gsum, float* gsq, int n){
    __shared__ float4 w3s[64*32];
    for (int e = threadIdx.x; e < 8192; e += 256) ((float*)w3s)[e] = w3[e];
    __syncthreads();
    int i = blockIdx.x*256 + threadIdx.x;
    bool valid = i < n;
    int i2 = valid ? i : 0;
    float h[64];
    const float4* src = (const float4*)(z2 + (size_t)i2*64);
#pragma unroll
    for (int q = 0; q < 16; q++){
        float4 v = src[q];
        h[q*4+0] = fmaxf(fmaf(v.x, a2[q*4+0], c2[q*4+0]), 0.f);
        h[q*4+1] = fmaxf(fmaf(v.y, a2[q*4+1], c2[q*4+1]), 0.f);
        h[q*4+2] = fmaxf(fmaf(v.z, a2[q*4+2], c2[q*4+2]), 0.f);
        h[q*4+3] = fmaxf(fmaf(v.w, a2[q*4+3], c2[q*4+3]), 0.f);
    }
#pragma unroll 1
    for (int cb = 0; cb < 128; cb += 32){
        float acc[32];
#pragma unroll
        for (int cc = 0; cc < 32; cc++) acc[cc] = b3[cb + cc];
#pragma unroll
        for (int k = 0; k < 64; k++){
            float v = h[k];
#pragma unroll
            for (int q = 0; q < 8; q++){
                float4 w = w3s[k*32 + (cb >> 2) + q];
                acc[q*4+0] = fmaf(v, w.x, acc[q*4+0]);
                acc[q*4+1] = fmaf(v, w.y, acc[q*4+1]);
                acc[q*4+2] = fmaf(v, w.z, acc[q*4+2]);
                acc[q*4+3] = fmaf(v, w.w, acc[q*4+3]);
            }
        }
        unsigned ob[16];
#pragma unroll
        for (int m = 0; m < 16; m++){
            unsigned short lo = f2bf(acc[2*m]);
            unsigned short hi = f2bf(acc[2*m+1]);
            ob[m] = (unsigned)lo | ((unsigned)hi << 16);
            acc[2*m]   = bf2f(lo);          // reuse acc for rounded values
            acc[2*m+1] = bf2f(hi);
        }
        if (valid){
            uint4* dst = (uint4*)(z3 + (size_t)i*128 + cb);
#pragma unroll
            for (int q = 0; q < 4; q++)
                dst[q] = make_uint4(ob[q*4], ob[q*4+1], ob[q*4+2], ob[q*4+3]);
        }
        reduce_stats<32>(acc, valid, gsum + cb, gsq + cb);
    }
}

// ---------- exclusive scan of cnt via block tickets (grid covers NCELL with guard) ----------
__global__ __launch_bounds__(256)
void k_off(const unsigned* __restrict__ cnt, unsigned* __restrict__ off,
           unsigned* __restrict__ gctr){
    __shared__ unsigned wtot[4];
    __shared__ unsigned wbase[4];
    int t = threadIdx.x;
    int lane = t & 63, w = t >> 6;
    int base = blockIdx.x * 1024 + t * 4;
    bool ok = base < NCELL;                 // NCELL % 4 == 0: quad all-in or all-out
    unsigned c0 = 0, c1 = 0, c2 = 0, c3 = 0;
    if (ok){ c0 = cnt[base]; c1 = cnt[base+1]; c2 = cnt[base+2]; c3 = cnt[base+3]; }
    unsigned tot = c0 + c1 + c2 + c3;
    unsigned incl = tot;
#pragma unroll
    for (int o = 1; o < 64; o <<= 1){
        unsigned v = __shfl_up(incl, o, 64);
        if (lane >= o) incl += v;
    }
    if (lane == 63) wtot[w] = incl;
    __syncthreads();
    if (t == 0){
        unsigned bt = wtot[0] + wtot[1] + wtot[2] + wtot[3];
        unsigned gb = atomicAdd(gctr, bt);
        unsigned s = 0;
#pragma unroll
        for (int q = 0; q < 4; q++){ wbase[q] = gb + s; s += wtot[q]; }
    }
    __syncthreads();
    if (ok){
        unsigned tb = wbase[w] + incl - tot;
        off[base]   = tb;
        off[base+1] = tb + c0;
        off[base+2] = tb + c0 + c1;
        off[base+3] = tb + c0 + c1 + c2;
    }
}

// ---------- fill per-cell point lists ----------
__global__ __launch_bounds__(256)
void k_fill(const int* __restrict__ ind, const unsigned* __restrict__ rank,
            const unsigned* __restrict__ off, unsigned* __restrict__ list, int n){
    int i = blockIdx.x*256 + threadIdx.x;
    if (i >= n) return;
    int bb = ind[(size_t)i*3], gx = ind[(size_t)i*3+1], gy = ind[(size_t)i*3+2];
    unsigned vox = ((unsigned)bb*GXd + (unsigned)gx)*GYd + (unsigned)gy;
    list[off[vox] + rank[i]] = (unsigned)i;
}

// ---------- layer4: 1 point/thread, cb loop PINNED (no unroll => no spill) ----------
__global__ __launch_bounds__(256, 2)
void k_l4(const unsigned short* __restrict__ z3,
          const float* __restrict__ w4, const float* __restrict__ b4,
          const float* __restrict__ a3, const float* __restrict__ c3,
          unsigned short* __restrict__ z4, int n){
    __shared__ float4 w4s[128*8];            // 16 KB: w4[k][32-ch slice]
    int i = blockIdx.x*256 + threadIdx.x;
    bool valid = i < n;
    int i2 = valid ? i : (n - 1);
    const uint4* rp = (const uint4*)(z3 + (size_t)i2*128);

#pragma unroll 1
    for (int cb = 0; cb < 8; cb++){
        // stage this 32-channel weight slice
        for (int e = threadIdx.x; e < 4096; e += 256){
            int k = e >> 5, cc = e & 31;
            ((float*)w4s)[e] = w4[k*256 + cb*32 + cc];
        }
        __syncthreads();

        float acc[32];
#pragma unroll
        for (int cc = 0; cc < 32; cc++) acc[cc] = b4[cb*32 + cc];

#pragma unroll
        for (int kb = 0; kb < 8; kb++){
            uint4 ua = rp[kb*2], ub = rp[kb*2+1];
            unsigned u[8] = {ua.x, ua.y, ua.z, ua.w, ub.x, ub.y, ub.z, ub.w};
            float h[16];
#pragma unroll
            for (int m = 0; m < 8; m++){
                int k = kb*16 + 2*m;
                h[2*m]   = fmaxf(fmaf(__uint_as_float(u[m] << 16),          a3[k],   c3[k]),   0.f);
                h[2*m+1] = fmaxf(fmaf(__uint_as_float(u[m] & 0xFFFF0000u), a3[k+1], c3[k+1]), 0.f);
            }
#pragma unroll
            for (int kk = 0; kk < 16; kk++){
                float v = h[kk];
#pragma unroll
                for (int q = 0; q < 8; q++){
                    float4 w = w4s[(kb*16 + kk)*8 + q];
                    acc[q*4+0] = fmaf(v, w.x, acc[q*4+0]);
                    acc[q*4+1] = fmaf(v, w.y, acc[q*4+1]);
                    acc[q*4+2] = fmaf(v, w.z, acc[q*4+2]);
                    acc[q*4+3] = fmaf(v, w.w, acc[q*4+3]);
                }
            }
        }

        if (valid){
            unsigned ob[16];
#pragma unroll
            for (int m = 0; m < 16; m++)
                ob[m] = (unsigned)f2bf(acc[2*m]) | ((unsigned)f2bf(acc[2*m+1]) << 16);
            uint4* d4 = (uint4*)(z4 + (size_t)i*256 + cb*32);
#pragma unroll
            for (int q = 0; q < 4; q++)
                d4[q] = make_uint4(ob[q*4], ob[q*4+1], ob[q*4+2], ob[q*4+3]);
        }
        __syncthreads();                      // w4s reused next cb
    }
}

// ---------- gather-max: one wave per cell, 4 channels per lane ----------
__global__ __launch_bounds__(256)
void k_gather(const unsigned* __restrict__ cnt, const unsigned* __restrict__ off,
              const unsigned* __restrict__ list,
              const unsigned short* __restrict__ z4,
              unsigned short* __restrict__ pooled){
    int lane = threadIdx.x & 63;
    int wid  = blockIdx.x*4 + (threadIdx.x >> 6);
    int wstride = gridDim.x * 4;
    for (int cell = wid; cell < NCELL; cell += wstride){
        unsigned cn = cnt[cell];
        unsigned o  = off[cell];
        float m0 = -__builtin_inff(), m1 = m0, m2 = m0, m3 = m0;
        for (unsigned p = 0; p < cn; p++){
            unsigned pid = list[o + p];
            uint2 u = *(const uint2*)(z4 + (size_t)pid*256 + lane*4);
            m0 = fmaxf(m0, __uint_as_float(u.x << 16));
            m1 = fmaxf(m1, __uint_as_float(u.x & 0xFFFF0000u));
            m2 = fmaxf(m2, __uint_as_float(u.y << 16));
            m3 = fmaxf(m3, __uint_as_float(u.y & 0xFFFF0000u));
        }
        if (cn == 0){ m0 = m1 = m2 = m3 = 0.f; }
        unsigned p0 = (__float_as_uint(m0) >> 16) | (__float_as_uint(m1) & 0xFFFF0000u);
        unsigned p1 = (__float_as_uint(m2) >> 16) | (__float_as_uint(m3) & 0xFFFF0000u);
        *(uint2*)(pooled + (size_t)cell*256 + lane*4) = make_uint2(p0, p1);
    }
}

// ---------- 3x3 maxpool: bf16 channel-last input, planar f32 output ----------
__global__ __launch_bounds__(256)
void k_maxpool(const unsigned short* __restrict__ pooled, float* __restrict__ out){
    int c   = threadIdx.x;
    int gy0 = blockIdx.x * 32;
    int gx0 = blockIdx.y * 4;
    int b   = blockIdx.z;
    const unsigned short* base = pooled + (size_t)b*GXY*256 + c;
    float* obase = out + ((size_t)b*258 + c)*GXY;
    float cmA[4], cmB[4];
#pragma unroll
    for (int g = 0; g < 4; g++){ cmA[g] = 0.f; cmB[g] = 0.f; }
    for (int tt = 0; tt < 34; tt++){
        int yy = gy0 - 1 + tt;
        bool yok = (unsigned)yy < (unsigned)GYd;
        float v[6];
#pragma unroll
        for (int r = 0; r < 6; r++){
            int xx = gx0 - 1 + r;
            float u = -__builtin_inff();
            if (yok && (unsigned)xx < (unsigned)GXd)
                u = bf2f(base[((size_t)xx*GYd + yy)*256]);
            v[r] = u;
        }
        float cm[4];
#pragma unroll
        for (int g = 0; g < 4; g++)
            cm[g] = fmaxf(fmaxf(v[g], v[g+1]), v[g+2]);
        if (tt >= 2){
            int oy = yy - 1;
            if (oy < gy0 + 32 && oy < GYd){
#pragma unroll
                for (int g = 0; g < 4; g++)
                    obase[(size_t)(gx0+g)*GYd + oy] = fmaxf(fmaxf(cmA[g], cmB[g]), cm[g]);
            }
        }
#pragma unroll
        for (int g = 0; g < 4; g++){ cmA[g] = cmB[g]; cmB[g] = cm[g]; }
    }
}

// ---------- residual channels ----------
__global__ __launch_bounds__(256)
void k_res(const unsigned* __restrict__ pres, float* __restrict__ out){
    int idx = blockIdx.x*256 + threadIdx.x;
    const int total = NBd*2*GXY;
    if (idx >= total) return;
    int gy = idx % GYd;
    int t  = idx / GYd;
    int gx = t % GXd;  t /= GXd;
    int r  = t & 1;
    int b  = t >> 1;
    unsigned u = pres[idx];
    float f = u ? unmapf(u) : 0.f;
    out[(((size_t)b*258 + 256 + r)*GXd + gx)*GYd + gy] = f;
}

extern "C" void kernel_launch(void* const* d_in, const int* in_sizes, int n_in,
                              void* d_out, int out_size, void* d_ws, size_t ws_size,
                              hipStream_t stream){
    (void)n_in; (void)out_size; (void)ws_size;
    const float* fea   = (const float*)d_in[0];
    const int*   ind   = (const int*)  d_in[1];
    const float* bn0_g = (const float*)d_in[2];
    const float* bn0_b = (const float*)d_in[3];
    const float* w1    = (const float*)d_in[4];
    const float* b1    = (const float*)d_in[5];
    const float* bn1_g = (const float*)d_in[6];
    const float* bn1_b = (const float*)d_in[7];
    const float* w2    = (const float*)d_in[8];
    const float* b2    = (const float*)d_in[9];
    const float* bn2_g = (const float*)d_in[10];
    const float* bn2_b = (const float*)d_in[11];
    const float* w3    = (const float*)d_in[12];
    const float* b3    = (const float*)d_in[13];
    const float* bn3_g = (const float*)d_in[14];
    const float* bn3_b = (const float*)d_in[15];
    const float* w4    = (const float*)d_in[16];
    const float* b4    = (const float*)d_in[17];

    int n = in_sizes[0] / 11;
    float invN = 1.0f / (float)n;

    // ---- ws layout ----
    const size_t Z4_B     = (size_t)240000*256*2;       // 122,880,000
    const size_t POOL_B   = (size_t)NCELL*256*2;        // 176,947,200
    const size_t PRES_B   = (size_t)NBd*2*GXY*4;        //   5,529,600
    const size_t CNT_B    = (size_t)NCELL*4;            //   2,764,800
    const size_t STAT_B   = 960*4;
    const size_t GCTR_B   = 256;

    char* base = (char*)d_ws;
    unsigned short* z4     = (unsigned short*)base;
    unsigned short* pooled = (unsigned short*)(base + Z4_B);
    // z1/z2/z3 alias the pooled region (dead before k_gather writes it)
    float*          z1     = (float*)(base + Z4_B);
    float*          z2     = (float*)(base + Z4_B + 30720000);
    unsigned short* z3     = (unsigned short*)(base + Z4_B + 92160000);
    unsigned* pres  = (unsigned*)(base + Z4_B + POOL_B);
    unsigned* cnt   = (unsigned*)((char*)pres + PRES_B);
    float*    stats = (float*)((char*)cnt + CNT_B);
    unsigned* gctr  = (unsigned*)((char*)stats + STAT_B);
    unsigned* off   = (unsigned*)((char*)gctr + GCTR_B);
    unsigned* list  = (unsigned*)((char*)off + CNT_B);
    unsigned* rank  = (unsigned*)((char*)list + (size_t)240000*4);

    float* sum0 = stats;       float* sq0 = stats + 16;
    float* sum1 = stats + 32;  float* sq1 = stats + 64;
    float* sum2 = stats + 96;  float* sq2 = stats + 160;
    float* sum3 = stats + 224; float* sq3 = stats + 352;
    float* a0 = stats + 480;   float* c0 = stats + 496;
    float* a1 = stats + 512;   float* c1 = stats + 544;
    float* a2 = stats + 576;   float* c2 = stats + 640;
    float* a3 = stats + 704;   float* c3 = stats + 832;

    // zero pres + cnt + stats + gctr in one shot (contiguous)
    hipMemsetAsync(pres, 0, PRES_B + CNT_B + STAT_B + GCTR_B, stream);

    int nb = (n + 255) / 256;
    k_stats0<<<nb, 256, 0, stream>>>(fea, sum0, sq0, n);
    k_fin<<<1, 128, 0, stream>>>(sum0, sq0, bn0_g, bn0_b, a0, c0, 9,  invN);
    k_l1<<<nb, 256, 0, stream>>>(fea, ind, w1, b1, a0, c0, z1, pres, cnt, rank, sum1, sq1, n);
    k_fin<<<1, 128, 0, stream>>>(sum1, sq1, bn1_g, bn1_b, a1, c1, 32, invN);
    k_l2<<<nb, 256, 0, stream>>>(z1, w2, b2, a1, c1, z2, sum2, sq2, n);
    k_fin<<<1, 128, 0, stream>>>(sum2, sq2, bn2_g, bn2_b, a2, c2, 64, invN);
    k_l3<<<nb, 256, 0, stream>>>(z2, w3, b3, a2, c2, z3, sum3, sq3, n);
    k_fin<<<1, 128, 0, stream>>>(sum3, sq3, bn3_g, bn3_b, a3, c3, 128, invN);

    k_off <<<(NCELL + 1023)/1024, 256, 0, stream>>>(cnt, off, gctr);
    k_fill<<<nb, 256, 0, stream>>>(ind, rank, off, list, n);

    k_l4<<<nb, 256, 0, stream>>>(z3, w4, b4, a3, c3, z4, n);

    k_gather<<<2048, 256, 0, stream>>>(cnt, off, list, z4, pooled);

    k_maxpool<<<dim3(12, 120, 2), 256, 0, stream>>>(pooled, (float*)d_out);
    k_res<<<(NBd*2*GXY + 255) / 256, 256, 0, stream>>>(pres, (float*)d_out);
}

// Round 7
// 2720.926 us; speedup vs baseline: 15.2697x; 15.2697x over previous
//
#include <hip/hip_runtime.h>
#include <cstdint>
#include <cstddef>

#define GXd 480
#define GYd 360
#define NBd 2
#define GXY (480*360)
#define NCELL (NBd*GXY)
#define EPSBN 1e-5f

typedef float  f32x4  __attribute__((ext_vector_type(4)));
typedef short  bf16x8 __attribute__((ext_vector_type(8)));

// ---------- order-preserving float <-> uint map (residual atomics only) ----------
__device__ __forceinline__ unsigned mapf(float f){
    unsigned u = __float_as_uint(f);
    return (u & 0x80000000u) ? ~u : (u | 0x80000000u);
}
__device__ __forceinline__ float unmapf(unsigned m){
    return (m & 0x80000000u) ? __uint_as_float(m ^ 0x80000000u)
                             : __uint_as_float(~m);
}

// ---------- bf16 helpers (RTN-even) ----------
__device__ __forceinline__ unsigned short f2bf(float f){
    unsigned u = __float_as_uint(f);
    unsigned r = (u + 0x7FFFu + ((u >> 16) & 1u)) >> 16;
    return (unsigned short)r;
}
__device__ __forceinline__ float bf2f(unsigned short s){
    return __uint_as_float(((unsigned)s) << 16);
}

// ---------- dense layer helper ----------
template<int DIN, int DOUT>
__device__ __forceinline__ void dense(const float (&in)[DIN], float (&out)[DOUT],
                                      const float* __restrict__ w,
                                      const float* __restrict__ b){
#pragma unroll
    for (int j = 0; j < DOUT; j++) out[j] = b[j];
#pragma unroll
    for (int d = 0; d < DIN; d++){
        float v = in[d];
#pragma unroll
        for (int j = 0; j < DOUT; j++) out[j] = fmaf(v, w[d*DOUT + j], out[j]);
    }
}

// ---------- block-level sum/sumsq reduction ----------
template<int D>
__device__ __forceinline__ void reduce_stats(const float (&h)[D], bool valid,
                                             float* __restrict__ gsum,
                                             float* __restrict__ gsq){
    __shared__ float ssum[D];
    __shared__ float ssq[D];
    int tid = threadIdx.x;
    for (int t = tid; t < D; t += 256){ ssum[t] = 0.f; ssq[t] = 0.f; }
    __syncthreads();
#pragma unroll
    for (int j = 0; j < D; j++){
        float v = valid ? h[j] : 0.f;
        float s = v * v;
#pragma unroll
        for (int o = 32; o > 0; o >>= 1){
            v += __shfl_down(v, o, 64);
            s += __shfl_down(s, o, 64);
        }
        if ((tid & 63) == 0){
            atomicAdd(&ssum[j], v);
            atomicAdd(&ssq[j], s);
        }
    }
    __syncthreads();
    for (int t = tid; t < D; t += 256){
        atomicAdd(&gsum[t], ssum[t]);
        atomicAdd(&gsq[t], ssq[t]);
    }
}

// ---------- stats of raw input columns 0..8 ----------
__global__ __launch_bounds__(256)
void k_stats0(const float* __restrict__ fea, float* gsum, float* gsq, int n){
    int i = blockIdx.x*256 + threadIdx.x;
    bool valid = i < n;
    int i2 = valid ? i : 0;
    float x[9];
#pragma unroll
    for (int d = 0; d < 9; d++) x[d] = fea[(size_t)i2*11 + d];
    reduce_stats<9>(x, valid, gsum, gsq);
}

// ---------- finalize BN ----------
__global__ void k_fin(const float* __restrict__ sum, const float* __restrict__ sq,
                      const float* __restrict__ g, const float* __restrict__ bb,
                      float* __restrict__ a_out, float* __restrict__ c_out,
                      int D, float invN){
    int t = threadIdx.x;
    if (t < D){
        float mu  = sum[t] * invN;
        float var = fmaf(-mu, mu, sq[t] * invN);
        float rs  = rsqrtf(var + EPSBN);
        float a   = rs * g[t];
        a_out[t] = a;
        c_out[t] = fmaf(-mu, a, bb[t]);
    }
}

// ---------- layer1: bn0 -> 9x32; z1; stats; voxel count+rank; res atomics ----------
__global__ __launch_bounds__(256)
void k_l1(const float* __restrict__ fea, const int* __restrict__ ind,
          const float* __restrict__ w1, const float* __restrict__ b1,
          const float* __restrict__ a0, const float* __restrict__ c0,
          float* __restrict__ z1, unsigned* __restrict__ pres,
          unsigned* __restrict__ cnt, unsigned* __restrict__ rank,
          float* gsum, float* gsq, int n){
    int i = blockIdx.x*256 + threadIdx.x;
    bool valid = i < n;
    int i2 = valid ? i : 0;
    float x[9];
#pragma unroll
    for (int d = 0; d < 9; d++) x[d] = fmaf(fea[(size_t)i2*11 + d], a0[d], c0[d]);
    float h[32];
    dense<9,32>(x, h, w1, b1);
    if (valid){
        float4* dst = (float4*)(z1 + (size_t)i*32);
#pragma unroll
        for (int q = 0; q < 8; q++)
            dst[q] = make_float4(h[q*4], h[q*4+1], h[q*4+2], h[q*4+3]);
        float r0 = fea[(size_t)i*11 + 9];
        float r1 = fea[(size_t)i*11 + 10];
        int bb = ind[(size_t)i*3 + 0];
        int gx = ind[(size_t)i*3 + 1];
        int gy = ind[(size_t)i*3 + 2];
        unsigned vox = ((unsigned)bb*GXd + (unsigned)gx)*GYd + (unsigned)gy;
        rank[i] = atomicAdd(&cnt[vox], 1u);
        size_t rbase = (size_t)bb*2*GXY + (size_t)gx*GYd + gy;
        atomicMax(pres + rbase,       mapf(r0));
        atomicMax(pres + rbase + GXY, mapf(r1));
    }
    reduce_stats<32>(h, valid, gsum, gsq);
}

// ---------- layer2 ----------
__global__ __launch_bounds__(256)
void k_l2(const float* __restrict__ z1,
          const float* __restrict__ w2, const float* __restrict__ b2,
          const float* __restrict__ a1, const float* __restrict__ c1,
          float* __restrict__ z2, float* gsum, float* gsq, int n){
    __shared__ float4 w2s[32*16];
    for (int e = threadIdx.x; e < 2048; e += 256) ((float*)w2s)[e] = w2[e];
    __syncthreads();
    int i = blockIdx.x*256 + threadIdx.x;
    bool valid = i < n;
    int i2 = valid ? i : 0;
    float h[32];
    const float4* src = (const float4*)(z1 + (size_t)i2*32);
#pragma unroll
    for (int q = 0; q < 8; q++){
        float4 v = src[q];
        h[q*4+0] = fmaxf(fmaf(v.x, a1[q*4+0], c1[q*4+0]), 0.f);
        h[q*4+1] = fmaxf(fmaf(v.y, a1[q*4+1], c1[q*4+1]), 0.f);
        h[q*4+2] = fmaxf(fmaf(v.z, a1[q*4+2], c1[q*4+2]), 0.f);
        h[q*4+3] = fmaxf(fmaf(v.w, a1[q*4+3], c1[q*4+3]), 0.f);
    }
    float acc[64];
#pragma unroll
    for (int j = 0; j < 64; j++) acc[j] = b2[j];
#pragma unroll
    for (int k = 0; k < 32; k++){
        float v = h[k];
#pragma unroll
        for (int q = 0; q < 16; q++){
            float4 w = w2s[k*16 + q];
            acc[q*4+0] = fmaf(v, w.x, acc[q*4+0]);
            acc[q*4+1] = fmaf(v, w.y, acc[q*4+1]);
            acc[q*4+2] = fmaf(v, w.z, acc[q*4+2]);
            acc[q*4+3] = fmaf(v, w.w, acc[q*4+3]);
        }
    }
    if (valid){
        float4* dst = (float4*)(z2 + (size_t)i*64);
#pragma unroll
        for (int q = 0; q < 16; q++)
            dst[q] = make_float4(acc[q*4], acc[q*4+1], acc[q*4+2], acc[q*4+3]);
    }
    reduce_stats<64>(acc, valid, gsum, gsq);
}

// ---------- layer3: z3 bf16; stats from rounded values; cb loop PINNED ----------
__global__ __launch_bounds__(256)
void k_l3(const float* __restrict__ z2,
          const float* __restrict__ w3, const float* __restrict__ b3,
          const float* __restrict__ a2, const float* __restrict__ c2,
          unsigned short* __restrict__ z3, float* gsum, float* gsq, int n){
    __shared__ float4 w3s[64*32];
    for (int e = threadIdx.x; e < 8192; e += 256) ((float*)w3s)[e] = w3[e];
    __syncthreads();
    int i = blockIdx.x*256 + threadIdx.x;
    bool valid = i < n;
    int i2 = valid ? i : 0;
    float h[64];
    const float4* src = (const float4*)(z2 + (size_t)i2*64);
#pragma unroll
    for (int q = 0; q < 16; q++){
        float4 v = src[q];
        h[q*4+0] = fmaxf(fmaf(v.x, a2[q*4+0], c2[q*4+0]), 0.f);
        h[q*4+1] = fmaxf(fmaf(v.y, a2[q*4+1], c2[q*4+1]), 0.f);
        h[q*4+2] = fmaxf(fmaf(v.z, a2[q*4+2], c2[q*4+2]), 0.f);
        h[q*4+3] = fmaxf(fmaf(v.w, a2[q*4+3], c2[q*4+3]), 0.f);
    }
#pragma unroll 1
    for (int cb = 0; cb < 128; cb += 32){
        float acc[32];
#pragma unroll
        for (int cc = 0; cc < 32; cc++) acc[cc] = b3[cb + cc];
#pragma unroll
        for (int k = 0; k < 64; k++){
            float v = h[k];
#pragma unroll
            for (int q = 0; q < 8; q++){
                float4 w = w3s[k*32 + (cb >> 2) + q];
                acc[q*4+0] = fmaf(v, w.x, acc[q*4+0]);
                acc[q*4+1] = fmaf(v, w.y, acc[q*4+1]);
                acc[q*4+2] = fmaf(v, w.z, acc[q*4+2]);
                acc[q*4+3] = fmaf(v, w.w, acc[q*4+3]);
            }
        }
        unsigned ob[16];
#pragma unroll
        for (int m = 0; m < 16; m++){
            unsigned short lo = f2bf(acc[2*m]);
            unsigned short hi = f2bf(acc[2*m+1]);
            ob[m] = (unsigned)lo | ((unsigned)hi << 16);
            acc[2*m]   = bf2f(lo);          // reuse acc for rounded values
            acc[2*m+1] = bf2f(hi);
        }
        if (valid){
            uint4* dst = (uint4*)(z3 + (size_t)i*128 + cb);
#pragma unroll
            for (int q = 0; q < 4; q++)
                dst[q] = make_uint4(ob[q*4], ob[q*4+1], ob[q*4+2], ob[q*4+3]);
        }
        reduce_stats<32>(acc, valid, gsum + cb, gsq + cb);
    }
}

// ---------- exclusive scan of cnt via block tickets ----------
__global__ __launch_bounds__(256)
void k_off(const unsigned* __restrict__ cnt, unsigned* __restrict__ off,
           unsigned* __restrict__ gctr){
    __shared__ unsigned wtot[4];
    __shared__ unsigned wbase[4];
    int t = threadIdx.x;
    int lane = t & 63, w = t >> 6;
    int base = blockIdx.x * 1024 + t * 4;
    bool ok = base < NCELL;
    unsigned c0 = 0, c1 = 0, c2 = 0, c3 = 0;
    if (ok){ c0 = cnt[base]; c1 = cnt[base+1]; c2 = cnt[base+2]; c3 = cnt[base+3]; }
    unsigned tot = c0 + c1 + c2 + c3;
    unsigned incl = tot;
#pragma unroll
    for (int o = 1; o < 64; o <<= 1){
        unsigned v = __shfl_up(incl, o, 64);
        if (lane >= o) incl += v;
    }
    if (lane == 63) wtot[w] = incl;
    __syncthreads();
    if (t == 0){
        unsigned bt = wtot[0] + wtot[1] + wtot[2] + wtot[3];
        unsigned gb = atomicAdd(gctr, bt);
        unsigned s = 0;
#pragma unroll
        for (int q = 0; q < 4; q++){ wbase[q] = gb + s; s += wtot[q]; }
    }
    __syncthreads();
    if (ok){
        unsigned tb = wbase[w] + incl - tot;
        off[base]   = tb;
        off[base+1] = tb + c0;
        off[base+2] = tb + c0 + c1;
        off[base+3] = tb + c0 + c1 + c2;
    }
}

// ---------- fill per-cell point lists ----------
__global__ __launch_bounds__(256)
void k_fill(const int* __restrict__ ind, const unsigned* __restrict__ rank,
            const unsigned* __restrict__ off, unsigned* __restrict__ list, int n){
    int i = blockIdx.x*256 + threadIdx.x;
    if (i >= n) return;
    int bb = ind[(size_t)i*3], gx = ind[(size_t)i*3+1], gy = ind[(size_t)i*3+2];
    unsigned vox = ((unsigned)bb*GXd + (unsigned)gx)*GYd + (unsigned)gy;
    list[off[vox] + rank[i]] = (unsigned)i;
}

// ---------- layer4 via MFMA: C[n x 256] = bn3relu(z3)[n x 128] @ w4 ----------
// block = 4 waves; wave w: 16 points x 256 ch. w4 staged bf16 transposed [c][k],
// XOR-swizzled (addr ^= (c&7)<<4) so B-frag = 1x ds_read_b128, 2-way max conflict.
// Fragment layouts (m89/m92-verified): A/B lane l holds 8 contiguous K at
// row/col (l&15), k-chunk (l>>4)*8; C: col = l&15, row = (l>>4)*4 + reg.
__global__ __launch_bounds__(256)
void k_l4(const unsigned short* __restrict__ z3,
          const float* __restrict__ w4, const float* __restrict__ b4,
          const float* __restrict__ a3, const float* __restrict__ c3,
          unsigned short* __restrict__ z4, int n){
    __shared__ short w4t[256*128];           // 64 KB: bf16 w4^T [c][k], swizzled
    int tid = threadIdx.x;
    for (int e = tid; e < 16384; e += 256){  // k-pairs; global reads coalesced
        int k2 = e >> 8;                     // 0..63
        int c  = e & 255;
        unsigned lo = f2bf(w4[(size_t)(2*k2)*256 + c]);
        unsigned hi = f2bf(w4[(size_t)(2*k2+1)*256 + c]);
        int addr = (c*256 + k2*4) ^ ((c & 7) << 4);
        *(unsigned*)((char*)w4t + addr) = lo | (hi << 16);
    }
    __syncthreads();

    int lane = tid & 63, wid = tid >> 6;
    int l15 = lane & 15, lg = lane >> 4;
    int p0 = blockIdx.x*64 + wid*16;
    int prow = p0 + l15;
    int prow2 = prow < n ? prow : (n - 1);
    const unsigned short* zrow = z3 + (size_t)prow2*128;

    f32x4 acc[16];
#pragma unroll
    for (int t = 0; t < 16; t++){
        float bv = b4[t*16 + l15];
        acc[t] = (f32x4){bv, bv, bv, bv};
    }

#pragma unroll
    for (int ks = 0; ks < 4; ks++){
        int kbase = ks*32 + lg*8;
        uint4 ua = *(const uint4*)(zrow + kbase);
        float4 av0 = *(const float4*)(a3 + kbase);
        float4 av1 = *(const float4*)(a3 + kbase + 4);
        float4 cv0 = *(const float4*)(c3 + kbase);
        float4 cv1 = *(const float4*)(c3 + kbase + 4);
        bf16x8 af;
        af[0] = (short)f2bf(fmaxf(fmaf(bf2f((unsigned short)(ua.x & 0xFFFFu)), av0.x, cv0.x), 0.f));
        af[1] = (short)f2bf(fmaxf(fmaf(bf2f((unsigned short)(ua.x >> 16)),     av0.y, cv0.y), 0.f));
        af[2] = (short)f2bf(fmaxf(fmaf(bf2f((unsigned short)(ua.y & 0xFFFFu)), av0.z, cv0.z), 0.f));
        af[3] = (short)f2bf(fmaxf(fmaf(bf2f((unsigned short)(ua.y >> 16)),     av0.w, cv0.w), 0.f));
        af[4] = (short)f2bf(fmaxf(fmaf(bf2f((unsigned short)(ua.z & 0xFFFFu)), av1.x, cv1.x), 0.f));
        af[5] = (short)f2bf(fmaxf(fmaf(bf2f((unsigned short)(ua.z >> 16)),     av1.y, cv1.y), 0.f));
        af[6] = (short)f2bf(fmaxf(fmaf(bf2f((unsigned short)(ua.w & 0xFFFFu)), av1.z, cv1.z), 0.f));
        af[7] = (short)f2bf(fmaxf(fmaf(bf2f((unsigned short)(ua.w >> 16)),     av1.w, cv1.w), 0.f));
#pragma unroll
        for (int t = 0; t < 16; t++){
            int c = t*16 + l15;
            int addr = (c*256 + kbase*2) ^ ((c & 7) << 4);
            bf16x8 bf = *(const bf16x8*)((const char*)w4t + addr);
            acc[t] = __builtin_amdgcn_mfma_f32_16x16x32_bf16(af, bf, acc[t], 0, 0, 0);
        }
    }

#pragma unroll
    for (int t = 0; t < 16; t++){
#pragma unroll
        for (int r = 0; r < 4; r++){
            int pr = p0 + lg*4 + r;
            if (pr < n)
                z4[(size_t)pr*256 + t*16 + l15] = f2bf(acc[t][r]);
        }
    }
}

// ---------- gather-max: one wave per cell, 4 channels per lane ----------
__global__ __launch_bounds__(256)
void k_gather(const unsigned* __restrict__ cnt, const unsigned* __restrict__ off,
              const unsigned* __restrict__ list,
              const unsigned short* __restrict__ z4,
              unsigned short* __restrict__ pooled){
    int lane = threadIdx.x & 63;
    int wid  = blockIdx.x*4 + (threadIdx.x >> 6);
    int wstride = gridDim.x * 4;
    for (int cell = wid; cell < NCELL; cell += wstride){
        unsigned cn = cnt[cell];
        unsigned o  = off[cell];
        float m0 = -__builtin_inff(), m1 = m0, m2 = m0, m3 = m0;
        for (unsigned p = 0; p < cn; p++){
            unsigned pid = list[o + p];
            uint2 u = *(const uint2*)(z4 + (size_t)pid*256 + lane*4);
            m0 = fmaxf(m0, __uint_as_float(u.x << 16));
            m1 = fmaxf(m1, __uint_as_float(u.x & 0xFFFF0000u));
            m2 = fmaxf(m2, __uint_as_float(u.y << 16));
            m3 = fmaxf(m3, __uint_as_float(u.y & 0xFFFF0000u));
        }
        if (cn == 0){ m0 = m1 = m2 = m3 = 0.f; }
        unsigned p0 = (__float_as_uint(m0) >> 16) | (__float_as_uint(m1) & 0xFFFF0000u);
        unsigned p1 = (__float_as_uint(m2) >> 16) | (__float_as_uint(m3) & 0xFFFF0000u);
        *(uint2*)(pooled + (size_t)cell*256 + lane*4) = make_uint2(p0, p1);
    }
}

// ---------- 3x3 maxpool: bf16 channel-last input, planar f32 output ----------
__global__ __launch_bounds__(256)
void k_maxpool(const unsigned short* __restrict__ pooled, float* __restrict__ out){
    int c   = threadIdx.x;
    int gy0 = blockIdx.x * 32;
    int gx0 = blockIdx.y * 4;
    int b   = blockIdx.z;
    const unsigned short* base = pooled + (size_t)b*GXY*256 + c;
    float* obase = out + ((size_t)b*258 + c)*GXY;
    float cmA[4], cmB[4];
#pragma unroll
    for (int g = 0; g < 4; g++){ cmA[g] = 0.f; cmB[g] = 0.f; }
    for (int tt = 0; tt < 34; tt++){
        int yy = gy0 - 1 + tt;
        bool yok = (unsigned)yy < (unsigned)GYd;
        float v[6];
#pragma unroll
        for (int r = 0; r < 6; r++){
            int xx = gx0 - 1 + r;
            float u = -__builtin_inff();
            if (yok && (unsigned)xx < (unsigned)GXd)
                u = bf2f(base[((size_t)xx*GYd + yy)*256]);
            v[r] = u;
        }
        float cm[4];
#pragma unroll
        for (int g = 0; g < 4; g++)
            cm[g] = fmaxf(fmaxf(v[g], v[g+1]), v[g+2]);
        if (tt >= 2){
            int oy = yy - 1;
            if (oy < gy0 + 32 && oy < GYd){
#pragma unroll
                for (int g = 0; g < 4; g++)
                    obase[(size_t)(gx0+g)*GYd + oy] = fmaxf(fmaxf(cmA[g], cmB[g]), cm[g]);
            }
        }
#pragma unroll
        for (int g = 0; g < 4; g++){ cmA[g] = cmB[g]; cmB[g] = cm[g]; }
    }
}

// ---------- residual channels ----------
__global__ __launch_bounds__(256)
void k_res(const unsigned* __restrict__ pres, float* __restrict__ out){
    int idx = blockIdx.x*256 + threadIdx.x;
    const int total = NBd*2*GXY;
    if (idx >= total) return;
    int gy = idx % GYd;
    int t  = idx / GYd;
    int gx = t % GXd;  t /= GXd;
    int r  = t & 1;
    int b  = t >> 1;
    unsigned u = pres[idx];
    float f = u ? unmapf(u) : 0.f;
    out[(((size_t)b*258 + 256 + r)*GXd + gx)*GYd + gy] = f;
}

extern "C" void kernel_launch(void* const* d_in, const int* in_sizes, int n_in,
                              void* d_out, int out_size, void* d_ws, size_t ws_size,
                              hipStream_t stream){
    (void)n_in; (void)out_size; (void)ws_size;
    const float* fea   = (const float*)d_in[0];
    const int*   ind   = (const int*)  d_in[1];
    const float* bn0_g = (const float*)d_in[2];
    const float* bn0_b = (const float*)d_in[3];
    const float* w1    = (const float*)d_in[4];
    const float* b1    = (const float*)d_in[5];
    const float* bn1_g = (const float*)d_in[6];
    const float* bn1_b = (const float*)d_in[7];
    const float* w2    = (const float*)d_in[8];
    const float* b2    = (const float*)d_in[9];
    const float* bn2_g = (const float*)d_in[10];
    const float* bn2_b = (const float*)d_in[11];
    const float* w3    = (const float*)d_in[12];
    const float* b3    = (const float*)d_in[13];
    const float* bn3_g = (const float*)d_in[14];
    const float* bn3_b = (const float*)d_in[15];
    const float* w4    = (const float*)d_in[16];
    const float* b4    = (const float*)d_in[17];

    int n = in_sizes[0] / 11;
    float invN = 1.0f / (float)n;

    // ---- ws layout ----
    const size_t Z4_B     = (size_t)240000*256*2;       // 122,880,000
    const size_t POOL_B   = (size_t)NCELL*256*2;        // 176,947,200
    const size_t PRES_B   = (size_t)NBd*2*GXY*4;        //   5,529,600
    const size_t CNT_B    = (size_t)NCELL*4;            //   2,764,800
    const size_t STAT_B   = 960*4;
    const size_t GCTR_B   = 256;

    char* base = (char*)d_ws;
    unsigned short* z4     = (unsigned short*)base;
    unsigned short* pooled = (unsigned short*)(base + Z4_B);
    // z1/z2/z3 alias the pooled region (dead before k_gather writes it)
    float*          z1     = (float*)(base + Z4_B);
    float*          z2     = (float*)(base + Z4_B + 30720000);
    unsigned short* z3     = (unsigned short*)(base + Z4_B + 92160000);
    unsigned* pres  = (unsigned*)(base + Z4_B + POOL_B);
    unsigned* cnt   = (unsigned*)((char*)pres + PRES_B);
    float*    stats = (float*)((char*)cnt + CNT_B);
    unsigned* gctr  = (unsigned*)((char*)stats + STAT_B);
    unsigned* off   = (unsigned*)((char*)gctr + GCTR_B);
    unsigned* list  = (unsigned*)((char*)off + CNT_B);
    unsigned* rank  = (unsigned*)((char*)list + (size_t)240000*4);

    float* sum0 = stats;       float* sq0 = stats + 16;
    float* sum1 = stats + 32;  float* sq1 = stats + 64;
    float* sum2 = stats + 96;  float* sq2 = stats + 160;
    float* sum3 = stats + 224; float* sq3 = stats + 352;
    float* a0 = stats + 480;   float* c0 = stats + 496;
    float* a1 = stats + 512;   float* c1 = stats + 544;
    float* a2 = stats + 576;   float* c2 = stats + 640;
    float* a3 = stats + 704;   float* c3 = stats + 832;

    hipMemsetAsync(pres, 0, PRES_B + CNT_B + STAT_B + GCTR_B, stream);

    int nb = (n + 255) / 256;
    k_stats0<<<nb, 256, 0, stream>>>(fea, sum0, sq0, n);
    k_fin<<<1, 128, 0, stream>>>(sum0, sq0, bn0_g, bn0_b, a0, c0, 9,  invN);
    k_l1<<<nb, 256, 0, stream>>>(fea, ind, w1, b1, a0, c0, z1, pres, cnt, rank, sum1, sq1, n);
    k_fin<<<1, 128, 0, stream>>>(sum1, sq1, bn1_g, bn1_b, a1, c1, 32, invN);
    k_l2<<<nb, 256, 0, stream>>>(z1, w2, b2, a1, c1, z2, sum2, sq2, n);
    k_fin<<<1, 128, 0, stream>>>(sum2, sq2, bn2_g, bn2_b, a2, c2, 64, invN);
    k_l3<<<nb, 256, 0, stream>>>(z2, w3, b3, a2, c2, z3, sum3, sq3, n);
    k_fin<<<1, 128, 0, stream>>>(sum3, sq3, bn3_g, bn3_b, a3, c3, 128, invN);

    k_off <<<(NCELL + 1023)/1024, 256, 0, stream>>>(cnt, off, gctr);
    k_fill<<<nb, 256, 0, stream>>>(ind, rank, off, list, n);

    k_l4<<<(n + 63) / 64, 256, 0, stream>>>(z3, w4, b4, a3, c3, z4, n);

    k_gather<<<2048, 256, 0, stream>>>(cnt, off, list, z4, pooled);

    k_maxpool<<<dim3(12, 120, 2), 256, 0, stream>>>(pooled, (float*)d_out);
    k_res<<<(NBd*2*GXY + 255) / 256, 256, 0, stream>>>(pres, (float*)d_out);
}

// Round 8
// 1478.194 us; speedup vs baseline: 28.1071x; 1.8407x over previous
//
#include <hip/hip_runtime.h>
#include <cstdint>
#include <cstddef>

#define GXd 480
#define GYd 360
#define NBd 2
#define GXY (480*360)
#define NCELL (NBd*GXY)
#define EPSBN 1e-5f

typedef float  f32x4  __attribute__((ext_vector_type(4)));
typedef short  bf16x8 __attribute__((ext_vector_type(8)));

// ---------- order-preserving float <-> uint map (residual atomics only) ----------
__device__ __forceinline__ unsigned mapf(float f){
    unsigned u = __float_as_uint(f);
    return (u & 0x80000000u) ? ~u : (u | 0x80000000u);
}
__device__ __forceinline__ float unmapf(unsigned m){
    return (m & 0x80000000u) ? __uint_as_float(m ^ 0x80000000u)
                             : __uint_as_float(~m);
}

// ---------- bf16 helpers (RTN-even) ----------
__device__ __forceinline__ unsigned short f2bf(float f){
    unsigned u = __float_as_uint(f);
    unsigned r = (u + 0x7FFFu + ((u >> 16) & 1u)) >> 16;
    return (unsigned short)r;
}
__device__ __forceinline__ float bf2f(unsigned short s){
    return __uint_as_float(((unsigned)s) << 16);
}

// ---------- dense layer helper ----------
template<int DIN, int DOUT>
__device__ __forceinline__ void dense(const float (&in)[DIN], float (&out)[DOUT],
                                      const float* __restrict__ w,
                                      const float* __restrict__ b){
#pragma unroll
    for (int j = 0; j < DOUT; j++) out[j] = b[j];
#pragma unroll
    for (int d = 0; d < DIN; d++){
        float v = in[d];
#pragma unroll
        for (int j = 0; j < DOUT; j++) out[j] = fmaf(v, w[d*DOUT + j], out[j]);
    }
}

// ---------- block-level sum/sumsq reduction ----------
template<int D>
__device__ __forceinline__ void reduce_stats(const float (&h)[D], bool valid,
                                             float* __restrict__ gsum,
                                             float* __restrict__ gsq){
    __shared__ float ssum[D];
    __shared__ float ssq[D];
    int tid = threadIdx.x;
    for (int t = tid; t < D; t += 256){ ssum[t] = 0.f; ssq[t] = 0.f; }
    __syncthreads();
#pragma unroll
    for (int j = 0; j < D; j++){
        float v = valid ? h[j] : 0.f;
        float s = v * v;
#pragma unroll
        for (int o = 32; o > 0; o >>= 1){
            v += __shfl_down(v, o, 64);
            s += __shfl_down(s, o, 64);
        }
        if ((tid & 63) == 0){
            atomicAdd(&ssum[j], v);
            atomicAdd(&ssq[j], s);
        }
    }
    __syncthreads();
    for (int t = tid; t < D; t += 256){
        atomicAdd(&gsum[t], ssum[t]);
        atomicAdd(&gsq[t], ssq[t]);
    }
}

// ---------- stats of raw input columns 0..8 ----------
__global__ __launch_bounds__(256)
void k_stats0(const float* __restrict__ fea, float* gsum, float* gsq, int n){
    int i = blockIdx.x*256 + threadIdx.x;
    bool valid = i < n;
    int i2 = valid ? i : 0;
    float x[9];
#pragma unroll
    for (int d = 0; d < 9; d++) x[d] = fea[(size_t)i2*11 + d];
    reduce_stats<9>(x, valid, gsum, gsq);
}

// ---------- finalize BN ----------
__global__ void k_fin(const float* __restrict__ sum, const float* __restrict__ sq,
                      const float* __restrict__ g, const float* __restrict__ bb,
                      float* __restrict__ a_out, float* __restrict__ c_out,
                      int D, float invN){
    int t = threadIdx.x;
    if (t < D){
        float mu  = sum[t] * invN;
        float var = fmaf(-mu, mu, sq[t] * invN);
        float rs  = rsqrtf(var + EPSBN);
        float a   = rs * g[t];
        a_out[t] = a;
        c_out[t] = fmaf(-mu, a, bb[t]);
    }
}

// ---------- layer1: bn0 -> 9x32; z1; stats; voxel count+rank; res atomics ----------
__global__ __launch_bounds__(256)
void k_l1(const float* __restrict__ fea, const int* __restrict__ ind,
          const float* __restrict__ w1, const float* __restrict__ b1,
          const float* __restrict__ a0, const float* __restrict__ c0,
          float* __restrict__ z1, unsigned* __restrict__ pres,
          unsigned* __restrict__ cnt, unsigned* __restrict__ rank,
          float* gsum, float* gsq, int n){
    int i = blockIdx.x*256 + threadIdx.x;
    bool valid = i < n;
    int i2 = valid ? i : 0;
    float x[9];
#pragma unroll
    for (int d = 0; d < 9; d++) x[d] = fmaf(fea[(size_t)i2*11 + d], a0[d], c0[d]);
    float h[32];
    dense<9,32>(x, h, w1, b1);
    if (valid){
        float4* dst = (float4*)(z1 + (size_t)i*32);
#pragma unroll
        for (int q = 0; q < 8; q++)
            dst[q] = make_float4(h[q*4], h[q*4+1], h[q*4+2], h[q*4+3]);
        float r0 = fea[(size_t)i*11 + 9];
        float r1 = fea[(size_t)i*11 + 10];
        int bb = ind[(size_t)i*3 + 0];
        int gx = ind[(size_t)i*3 + 1];
        int gy = ind[(size_t)i*3 + 2];
        unsigned vox = ((unsigned)bb*GXd + (unsigned)gx)*GYd + (unsigned)gy;
        rank[i] = atomicAdd(&cnt[vox], 1u);
        size_t rbase = (size_t)bb*2*GXY + (size_t)gx*GYd + gy;
        atomicMax(pres + rbase,       mapf(r0));
        atomicMax(pres + rbase + GXY, mapf(r1));
    }
    reduce_stats<32>(h, valid, gsum, gsq);
}

// ---------- layer2 ----------
__global__ __launch_bounds__(256)
void k_l2(const float* __restrict__ z1,
          const float* __restrict__ w2, const float* __restrict__ b2,
          const float* __restrict__ a1, const float* __restrict__ c1,
          float* __restrict__ z2, float* gsum, float* gsq, int n){
    __shared__ float4 w2s[32*16];
    for (int e = threadIdx.x; e < 2048; e += 256) ((float*)w2s)[e] = w2[e];
    __syncthreads();
    int i = blockIdx.x*256 + threadIdx.x;
    bool valid = i < n;
    int i2 = valid ? i : 0;
    float h[32];
    const float4* src = (const float4*)(z1 + (size_t)i2*32);
#pragma unroll
    for (int q = 0; q < 8; q++){
        float4 v = src[q];
        h[q*4+0] = fmaxf(fmaf(v.x, a1[q*4+0], c1[q*4+0]), 0.f);
        h[q*4+1] = fmaxf(fmaf(v.y, a1[q*4+1], c1[q*4+1]), 0.f);
        h[q*4+2] = fmaxf(fmaf(v.z, a1[q*4+2], c1[q*4+2]), 0.f);
        h[q*4+3] = fmaxf(fmaf(v.w, a1[q*4+3], c1[q*4+3]), 0.f);
    }
    float acc[64];
#pragma unroll
    for (int j = 0; j < 64; j++) acc[j] = b2[j];
#pragma unroll
    for (int k = 0; k < 32; k++){
        float v = h[k];
#pragma unroll
        for (int q = 0; q < 16; q++){
            float4 w = w2s[k*16 + q];
            acc[q*4+0] = fmaf(v, w.x, acc[q*4+0]);
            acc[q*4+1] = fmaf(v, w.y, acc[q*4+1]);
            acc[q*4+2] = fmaf(v, w.z, acc[q*4+2]);
            acc[q*4+3] = fmaf(v, w.w, acc[q*4+3]);
        }
    }
    if (valid){
        float4* dst = (float4*)(z2 + (size_t)i*64);
#pragma unroll
        for (int q = 0; q < 16; q++)
            dst[q] = make_float4(acc[q*4], acc[q*4+1], acc[q*4+2], acc[q*4+3]);
    }
    reduce_stats<64>(acc, valid, gsum, gsq);
}

// ---------- layer3: z3 bf16; stats from rounded values; cb loop PINNED ----------
__global__ __launch_bounds__(256)
void k_l3(const float* __restrict__ z2,
          const float* __restrict__ w3, const float* __restrict__ b3,
          const float* __restrict__ a2, const float* __restrict__ c2,
          unsigned short* __restrict__ z3, float* gsum, float* gsq, int n){
    __shared__ float4 w3s[64*32];
    for (int e = threadIdx.x; e < 8192; e += 256) ((float*)w3s)[e] = w3[e];
    __syncthreads();
    int i = blockIdx.x*256 + threadIdx.x;
    bool valid = i < n;
    int i2 = valid ? i : 0;
    float h[64];
    const float4* src = (const float4*)(z2 + (size_t)i2*64);
#pragma unroll
    for (int q = 0; q < 16; q++){
        float4 v = src[q];
        h[q*4+0] = fmaxf(fmaf(v.x, a2[q*4+0], c2[q*4+0]), 0.f);
        h[q*4+1] = fmaxf(fmaf(v.y, a2[q*4+1], c2[q*4+1]), 0.f);
        h[q*4+2] = fmaxf(fmaf(v.z, a2[q*4+2], c2[q*4+2]), 0.f);
        h[q*4+3] = fmaxf(fmaf(v.w, a2[q*4+3], c2[q*4+3]), 0.f);
    }
#pragma unroll 1
    for (int cb = 0; cb < 128; cb += 32){
        float acc[32];
#pragma unroll
        for (int cc = 0; cc < 32; cc++) acc[cc] = b3[cb + cc];
#pragma unroll
        for (int k = 0; k < 64; k++){
            float v = h[k];
#pragma unroll
            for (int q = 0; q < 8; q++){
                float4 w = w3s[k*32 + (cb >> 2) + q];
                acc[q*4+0] = fmaf(v, w.x, acc[q*4+0]);
                acc[q*4+1] = fmaf(v, w.y, acc[q*4+1]);
                acc[q*4+2] = fmaf(v, w.z, acc[q*4+2]);
                acc[q*4+3] = fmaf(v, w.w, acc[q*4+3]);
            }
        }
        unsigned ob[16];
#pragma unroll
        for (int m = 0; m < 16; m++){
            unsigned short lo = f2bf(acc[2*m]);
            unsigned short hi = f2bf(acc[2*m+1]);
            ob[m] = (unsigned)lo | ((unsigned)hi << 16);
            acc[2*m]   = bf2f(lo);          // reuse acc for rounded values
            acc[2*m+1] = bf2f(hi);
        }
        if (valid){
            uint4* dst = (uint4*)(z3 + (size_t)i*128 + cb);
#pragma unroll
            for (int q = 0; q < 4; q++)
                dst[q] = make_uint4(ob[q*4], ob[q*4+1], ob[q*4+2], ob[q*4+3]);
        }
        reduce_stats<32>(acc, valid, gsum + cb, gsq + cb);
    }
}

// ---------- exclusive scan of cnt via block tickets ----------
__global__ __launch_bounds__(256)
void k_off(const unsigned* __restrict__ cnt, unsigned* __restrict__ off,
           unsigned* __restrict__ gctr){
    __shared__ unsigned wtot[4];
    __shared__ unsigned wbase[4];
    int t = threadIdx.x;
    int lane = t & 63, w = t >> 6;
    int base = blockIdx.x * 1024 + t * 4;
    bool ok = base < NCELL;
    unsigned c0 = 0, c1 = 0, c2 = 0, c3 = 0;
    if (ok){ c0 = cnt[base]; c1 = cnt[base+1]; c2 = cnt[base+2]; c3 = cnt[base+3]; }
    unsigned tot = c0 + c1 + c2 + c3;
    unsigned incl = tot;
#pragma unroll
    for (int o = 1; o < 64; o <<= 1){
        unsigned v = __shfl_up(incl, o, 64);
        if (lane >= o) incl += v;
    }
    if (lane == 63) wtot[w] = incl;
    __syncthreads();
    if (t == 0){
        unsigned bt = wtot[0] + wtot[1] + wtot[2] + wtot[3];
        unsigned gb = atomicAdd(gctr, bt);
        unsigned s = 0;
#pragma unroll
        for (int q = 0; q < 4; q++){ wbase[q] = gb + s; s += wtot[q]; }
    }
    __syncthreads();
    if (ok){
        unsigned tb = wbase[w] + incl - tot;
        off[base]   = tb;
        off[base+1] = tb + c0;
        off[base+2] = tb + c0 + c1;
        off[base+3] = tb + c0 + c1 + c2;
    }
}

// ---------- fill per-cell point lists ----------
__global__ __launch_bounds__(256)
void k_fill(const int* __restrict__ ind, const unsigned* __restrict__ rank,
            const unsigned* __restrict__ off, unsigned* __restrict__ list, int n){
    int i = blockIdx.x*256 + threadIdx.x;
    if (i >= n) return;
    int bb = ind[(size_t)i*3], gx = ind[(size_t)i*3+1], gy = ind[(size_t)i*3+2];
    unsigned vox = ((unsigned)bb*GXd + (unsigned)gx)*GYd + (unsigned)gy;
    list[off[vox] + rank[i]] = (unsigned)i;
}

// ---------- layer4 via MFMA: C[n x 256] = bn3relu(z3)[n x 128] @ w4 ----------
__global__ __launch_bounds__(256)
void k_l4(const unsigned short* __restrict__ z3,
          const float* __restrict__ w4, const float* __restrict__ b4,
          const float* __restrict__ a3, const float* __restrict__ c3,
          unsigned short* __restrict__ z4, int n){
    __shared__ short w4t[256*128];           // 64 KB: bf16 w4^T [c][k], swizzled
    int tid = threadIdx.x;
    for (int e = tid; e < 16384; e += 256){  // k-pairs; global reads coalesced
        int k2 = e >> 8;                     // 0..63
        int c  = e & 255;
        unsigned lo = f2bf(w4[(size_t)(2*k2)*256 + c]);
        unsigned hi = f2bf(w4[(size_t)(2*k2+1)*256 + c]);
        int addr = (c*256 + k2*4) ^ ((c & 7) << 4);
        *(unsigned*)((char*)w4t + addr) = lo | (hi << 16);
    }
    __syncthreads();

    int lane = tid & 63, wid = tid >> 6;
    int l15 = lane & 15, lg = lane >> 4;
    int p0 = blockIdx.x*64 + wid*16;
    int prow = p0 + l15;
    int prow2 = prow < n ? prow : (n - 1);
    const unsigned short* zrow = z3 + (size_t)prow2*128;

    f32x4 acc[16];
#pragma unroll
    for (int t = 0; t < 16; t++){
        float bv = b4[t*16 + l15];
        acc[t] = (f32x4){bv, bv, bv, bv};
    }

#pragma unroll
    for (int ks = 0; ks < 4; ks++){
        int kbase = ks*32 + lg*8;
        uint4 ua = *(const uint4*)(zrow + kbase);
        float4 av0 = *(const float4*)(a3 + kbase);
        float4 av1 = *(const float4*)(a3 + kbase + 4);
        float4 cv0 = *(const float4*)(c3 + kbase);
        float4 cv1 = *(const float4*)(c3 + kbase + 4);
        bf16x8 af;
        af[0] = (short)f2bf(fmaxf(fmaf(bf2f((unsigned short)(ua.x & 0xFFFFu)), av0.x, cv0.x), 0.f));
        af[1] = (short)f2bf(fmaxf(fmaf(bf2f((unsigned short)(ua.x >> 16)),     av0.y, cv0.y), 0.f));
        af[2] = (short)f2bf(fmaxf(fmaf(bf2f((unsigned short)(ua.y & 0xFFFFu)), av0.z, cv0.z), 0.f));
        af[3] = (short)f2bf(fmaxf(fmaf(bf2f((unsigned short)(ua.y >> 16)),     av0.w, cv0.w), 0.f));
        af[4] = (short)f2bf(fmaxf(fmaf(bf2f((unsigned short)(ua.z & 0xFFFFu)), av1.x, cv1.x), 0.f));
        af[5] = (short)f2bf(fmaxf(fmaf(bf2f((unsigned short)(ua.z >> 16)),     av1.y, cv1.y), 0.f));
        af[6] = (short)f2bf(fmaxf(fmaf(bf2f((unsigned short)(ua.w & 0xFFFFu)), av1.z, cv1.z), 0.f));
        af[7] = (short)f2bf(fmaxf(fmaf(bf2f((unsigned short)(ua.w >> 16)),     av1.w, cv1.w), 0.f));
#pragma unroll
        for (int t = 0; t < 16; t++){
            int c = t*16 + l15;
            int addr = (c*256 + kbase*2) ^ ((c & 7) << 4);
            bf16x8 bf = *(const bf16x8*)((const char*)w4t + addr);
            acc[t] = __builtin_amdgcn_mfma_f32_16x16x32_bf16(af, bf, acc[t], 0, 0, 0);
        }
    }

#pragma unroll
    for (int t = 0; t < 16; t++){
#pragma unroll
        for (int r = 0; r < 4; r++){
            int pr = p0 + lg*4 + r;
            if (pr < n)
                z4[(size_t)pr*256 + t*16 + l15] = f2bf(acc[t][r]);
        }
    }
}

// ---------- gather-max: one wave per cell, 4 channels per lane ----------
__global__ __launch_bounds__(256)
void k_gather(const unsigned* __restrict__ cnt, const unsigned* __restrict__ off,
              const unsigned* __restrict__ list,
              const unsigned short* __restrict__ z4,
              unsigned short* __restrict__ pooled){
    int lane = threadIdx.x & 63;
    int wid  = blockIdx.x*4 + (threadIdx.x >> 6);
    int wstride = gridDim.x * 4;
    for (int cell = wid; cell < NCELL; cell += wstride){
        unsigned cn = cnt[cell];
        unsigned o  = off[cell];
        float m0 = -__builtin_inff(), m1 = m0, m2 = m0, m3 = m0;
        for (unsigned p = 0; p < cn; p++){
            unsigned pid = list[o + p];
            uint2 u = *(const uint2*)(z4 + (size_t)pid*256 + lane*4);
            m0 = fmaxf(m0, __uint_as_float(u.x << 16));
            m1 = fmaxf(m1, __uint_as_float(u.x & 0xFFFF0000u));
            m2 = fmaxf(m2, __uint_as_float(u.y << 16));
            m3 = fmaxf(m3, __uint_as_float(u.y & 0xFFFF0000u));
        }
        if (cn == 0){ m0 = m1 = m2 = m3 = 0.f; }
        unsigned p0 = (__float_as_uint(m0) >> 16) | (__float_as_uint(m1) & 0xFFFF0000u);
        unsigned p1 = (__float_as_uint(m2) >> 16) | (__float_as_uint(m3) & 0xFFFF0000u);
        *(uint2*)(pooled + (size_t)cell*256 + lane*4) = make_uint2(p0, p1);
    }
}

// ---------- 3x3 maxpool: channel-last bf16 in; LDS transpose; planar f32 out ----------
// Phase 1 (unchanged compute): c = tid, rolling 3x3 max over 4 gx x 32 gy; store
// bf16 to LDS tile [g][y][c] (lossless: max of bf16 values is one of them).
// Phase 2: thread owns (c,g); float4 stores of 4 contiguous gy -> full-line fills
// within 4 consecutive wave instructions (kills the 15x write amplification).
__global__ __launch_bounds__(256)
void k_maxpool(const unsigned short* __restrict__ pooled, float* __restrict__ out){
    __shared__ unsigned short tile[4*32*256];   // 64 KB
    int c   = threadIdx.x;
    int gy0 = blockIdx.x * 32;
    int gx0 = blockIdx.y * 4;
    int b   = blockIdx.z;
    const unsigned short* base = pooled + (size_t)b*GXY*256 + c;
    float cmA[4], cmB[4];
#pragma unroll
    for (int g = 0; g < 4; g++){ cmA[g] = 0.f; cmB[g] = 0.f; }
    for (int tt = 0; tt < 34; tt++){
        int yy = gy0 - 1 + tt;
        bool yok = (unsigned)yy < (unsigned)GYd;
        float v[6];
#pragma unroll
        for (int r = 0; r < 6; r++){
            int xx = gx0 - 1 + r;
            float u = -__builtin_inff();
            if (yok && (unsigned)xx < (unsigned)GXd)
                u = bf2f(base[((size_t)xx*GYd + yy)*256]);
            v[r] = u;
        }
        float cm[4];
#pragma unroll
        for (int g = 0; g < 4; g++)
            cm[g] = fmaxf(fmaxf(v[g], v[g+1]), v[g+2]);
        if (tt >= 2){
            int oy = yy - 1;
            if (oy < gy0 + 32 && oy < GYd){
                int yl = oy - gy0;
#pragma unroll
                for (int g = 0; g < 4; g++)
                    tile[(g*32 + yl)*256 + c] = f2bf(fmaxf(fmaxf(cmA[g], cmB[g]), cm[g]));
            }
        }
#pragma unroll
        for (int g = 0; g < 4; g++){ cmA[g] = cmB[g]; cmB[g] = cm[g]; }
    }
    __syncthreads();
    int ymax = GYd - gy0; if (ymax > 32) ymax = 32;   // 32 or 8 (both %4==0)
    // p = tid + 256*it : c2 = tid, g = it
#pragma unroll 1
    for (int g = 0; g < 4; g++){
        float* dst = out + ((size_t)b*258 + c)*GXY + (size_t)(gx0+g)*GYd + gy0;
        const unsigned short* srcl = &tile[g*32*256 + c];
#pragma unroll 1
        for (int y = 0; y < ymax; y += 4){
            float4 o4;
            o4.x = bf2f(srcl[(y+0)*256]);
            o4.y = bf2f(srcl[(y+1)*256]);
            o4.z = bf2f(srcl[(y+2)*256]);
            o4.w = bf2f(srcl[(y+3)*256]);
            *(float4*)(dst + y) = o4;
        }
    }
}

// ---------- residual channels ----------
__global__ __launch_bounds__(256)
void k_res(const unsigned* __restrict__ pres, float* __restrict__ out){
    int idx = blockIdx.x*256 + threadIdx.x;
    const int total = NBd*2*GXY;
    if (idx >= total) return;
    int gy = idx % GYd;
    int t  = idx / GYd;
    int gx = t % GXd;  t /= GXd;
    int r  = t & 1;
    int b  = t >> 1;
    unsigned u = pres[idx];
    float f = u ? unmapf(u) : 0.f;
    out[(((size_t)b*258 + 256 + r)*GXd + gx)*GYd + gy] = f;
}

extern "C" void kernel_launch(void* const* d_in, const int* in_sizes, int n_in,
                              void* d_out, int out_size, void* d_ws, size_t ws_size,
                              hipStream_t stream){
    (void)n_in; (void)out_size; (void)ws_size;
    const float* fea   = (const float*)d_in[0];
    const int*   ind   = (const int*)  d_in[1];
    const float* bn0_g = (const float*)d_in[2];
    const float* bn0_b = (const float*)d_in[3];
    const float* w1    = (const float*)d_in[4];
    const float* b1    = (const float*)d_in[5];
    const float* bn1_g = (const float*)d_in[6];
    const float* bn1_b = (const float*)d_in[7];
    const float* w2    = (const float*)d_in[8];
    const float* b2    = (const float*)d_in[9];
    const float* bn2_g = (const float*)d_in[10];
    const float* bn2_b = (const float*)d_in[11];
    const float* w3    = (const float*)d_in[12];
    const float* b3    = (const float*)d_in[13];
    const float* bn3_g = (const float*)d_in[14];
    const float* bn3_b = (const float*)d_in[15];
    const float* w4    = (const float*)d_in[16];
    const float* b4    = (const float*)d_in[17];

    int n = in_sizes[0] / 11;
    float invN = 1.0f / (float)n;

    // ---- ws layout ----
    const size_t Z4_B     = (size_t)240000*256*2;       // 122,880,000
    const size_t POOL_B   = (size_t)NCELL*256*2;        // 176,947,200
    const size_t PRES_B   = (size_t)NBd*2*GXY*4;        //   5,529,600
    const size_t CNT_B    = (size_t)NCELL*4;            //   2,764,800
    const size_t STAT_B   = 960*4;
    const size_t GCTR_B   = 256;

    char* base = (char*)d_ws;
    unsigned short* z4     = (unsigned short*)base;
    unsigned short* pooled = (unsigned short*)(base + Z4_B);
    // z1/z2/z3 alias the pooled region (dead before k_gather writes it)
    float*          z1     = (float*)(base + Z4_B);
    float*          z2     = (float*)(base + Z4_B + 30720000);
    unsigned short* z3     = (unsigned short*)(base + Z4_B + 92160000);
    unsigned* pres  = (unsigned*)(base + Z4_B + POOL_B);
    unsigned* cnt   = (unsigned*)((char*)pres + PRES_B);
    float*    stats = (float*)((char*)cnt + CNT_B);
    unsigned* gctr  = (unsigned*)((char*)stats + STAT_B);
    unsigned* off   = (unsigned*)((char*)gctr + GCTR_B);
    unsigned* list  = (unsigned*)((char*)off + CNT_B);
    unsigned* rank  = (unsigned*)((char*)list + (size_t)240000*4);

    float* sum0 = stats;       float* sq0 = stats + 16;
    float* sum1 = stats + 32;  float* sq1 = stats + 64;
    float* sum2 = stats + 96;  float* sq2 = stats + 160;
    float* sum3 = stats + 224; float* sq3 = stats + 352;
    float* a0 = stats + 480;   float* c0 = stats + 496;
    float* a1 = stats + 512;   float* c1 = stats + 544;
    float* a2 = stats + 576;   float* c2 = stats + 640;
    float* a3 = stats + 704;   float* c3 = stats + 832;

    hipMemsetAsync(pres, 0, PRES_B + CNT_B + STAT_B + GCTR_B, stream);

    int nb = (n + 255) / 256;
    k_stats0<<<nb, 256, 0, stream>>>(fea, sum0, sq0, n);
    k_fin<<<1, 128, 0, stream>>>(sum0, sq0, bn0_g, bn0_b, a0, c0, 9,  invN);
    k_l1<<<nb, 256, 0, stream>>>(fea, ind, w1, b1, a0, c0, z1, pres, cnt, rank, sum1, sq1, n);
    k_fin<<<1, 128, 0, stream>>>(sum1, sq1, bn1_g, bn1_b, a1, c1, 32, invN);
    k_l2<<<nb, 256, 0, stream>>>(z1, w2, b2, a1, c1, z2, sum2, sq2, n);
    k_fin<<<1, 128, 0, stream>>>(sum2, sq2, bn2_g, bn2_b, a2, c2, 64, invN);
    k_l3<<<nb, 256, 0, stream>>>(z2, w3, b3, a2, c2, z3, sum3, sq3, n);
    k_fin<<<1, 128, 0, stream>>>(sum3, sq3, bn3_g, bn3_b, a3, c3, 128, invN);

    k_off <<<(NCELL + 1023)/1024, 256, 0, stream>>>(cnt, off, gctr);
    k_fill<<<nb, 256, 0, stream>>>(ind, rank, off, list, n);

    k_l4<<<(n + 63) / 64, 256, 0, stream>>>(z3, w4, b4, a3, c3, z4, n);

    k_gather<<<2048, 256, 0, stream>>>(cnt, off, list, z4, pooled);

    k_maxpool<<<dim3(12, 120, 2), 256, 0, stream>>>(pooled, (float*)d_out);
    k_res<<<(NBd*2*GXY + 255) / 256, 256, 0, stream>>>(pres, (float*)d_out);
}

// Round 9
// 1182.940 us; speedup vs baseline: 35.1225x; 1.2496x over previous
//
#include <hip/hip_runtime.h>
#include <cstdint>
#include <cstddef>

#define GXd 480
#define GYd 360
#define NBd 2
#define GXY (480*360)
#define NCELL (NBd*GXY)
#define EPSBN 1e-5f

typedef float  f32x4  __attribute__((ext_vector_type(4)));
typedef short  bf16x8 __attribute__((ext_vector_type(8)));

// ---------- order-preserving float <-> uint map (residual atomics only) ----------
__device__ __forceinline__ unsigned mapf(float f){
    unsigned u = __float_as_uint(f);
    return (u & 0x80000000u) ? ~u : (u | 0x80000000u);
}
__device__ __forceinline__ float unmapf(unsigned m){
    return (m & 0x80000000u) ? __uint_as_float(m ^ 0x80000000u)
                             : __uint_as_float(~m);
}

// ---------- bf16 helpers (RTN-even) ----------
__device__ __forceinline__ unsigned short f2bf(float f){
    unsigned u = __float_as_uint(f);
    unsigned r = (u + 0x7FFFu + ((u >> 16) & 1u)) >> 16;
    return (unsigned short)r;
}
__device__ __forceinline__ float bf2f(unsigned short s){
    return __uint_as_float(((unsigned)s) << 16);
}

// ---------- dense layer helper ----------
template<int DIN, int DOUT>
__device__ __forceinline__ void dense(const float (&in)[DIN], float (&out)[DOUT],
                                      const float* __restrict__ w,
                                      const float* __restrict__ b){
#pragma unroll
    for (int j = 0; j < DOUT; j++) out[j] = b[j];
#pragma unroll
    for (int d = 0; d < DIN; d++){
        float v = in[d];
#pragma unroll
        for (int j = 0; j < DOUT; j++) out[j] = fmaf(v, w[d*DOUT + j], out[j]);
    }
}

// ---------- block-level sum/sumsq reduction ----------
template<int D>
__device__ __forceinline__ void reduce_stats(const float (&h)[D], bool valid,
                                             float* __restrict__ gsum,
                                             float* __restrict__ gsq){
    __shared__ float ssum[D];
    __shared__ float ssq[D];
    int tid = threadIdx.x;
    for (int t = tid; t < D; t += 256){ ssum[t] = 0.f; ssq[t] = 0.f; }
    __syncthreads();
#pragma unroll
    for (int j = 0; j < D; j++){
        float v = valid ? h[j] : 0.f;
        float s = v * v;
#pragma unroll
        for (int o = 32; o > 0; o >>= 1){
            v += __shfl_down(v, o, 64);
            s += __shfl_down(s, o, 64);
        }
        if ((tid & 63) == 0){
            atomicAdd(&ssum[j], v);
            atomicAdd(&ssq[j], s);
        }
    }
    __syncthreads();
    for (int t = tid; t < D; t += 256){
        atomicAdd(&gsum[t], ssum[t]);
        atomicAdd(&gsq[t], ssq[t]);
    }
}

// ---------- stats of raw input columns 0..8 ----------
__global__ __launch_bounds__(256)
void k_stats0(const float* __restrict__ fea, float* gsum, float* gsq, int n){
    int i = blockIdx.x*256 + threadIdx.x;
    bool valid = i < n;
    int i2 = valid ? i : 0;
    float x[9];
#pragma unroll
    for (int d = 0; d < 9; d++) x[d] = fea[(size_t)i2*11 + d];
    reduce_stats<9>(x, valid, gsum, gsq);
}

// ---------- finalize BN ----------
__global__ void k_fin(const float* __restrict__ sum, const float* __restrict__ sq,
                      const float* __restrict__ g, const float* __restrict__ bb,
                      float* __restrict__ a_out, float* __restrict__ c_out,
                      int D, float invN){
    int t = threadIdx.x;
    if (t < D){
        float mu  = sum[t] * invN;
        float var = fmaf(-mu, mu, sq[t] * invN);
        float rs  = rsqrtf(var + EPSBN);
        float a   = rs * g[t];
        a_out[t] = a;
        c_out[t] = fmaf(-mu, a, bb[t]);
    }
}

// ---------- layer1: bn0 -> 9x32; z1; stats; voxel count+rank; res atomics ----------
__global__ __launch_bounds__(256)
void k_l1(const float* __restrict__ fea, const int* __restrict__ ind,
          const float* __restrict__ w1, const float* __restrict__ b1,
          const float* __restrict__ a0, const float* __restrict__ c0,
          float* __restrict__ z1, unsigned* __restrict__ pres,
          unsigned* __restrict__ cnt, unsigned* __restrict__ rank,
          float* gsum, float* gsq, int n){
    int i = blockIdx.x*256 + threadIdx.x;
    bool valid = i < n;
    int i2 = valid ? i : 0;
    float x[9];
#pragma unroll
    for (int d = 0; d < 9; d++) x[d] = fmaf(fea[(size_t)i2*11 + d], a0[d], c0[d]);
    float h[32];
    dense<9,32>(x, h, w1, b1);
    if (valid){
        float4* dst = (float4*)(z1 + (size_t)i*32);
#pragma unroll
        for (int q = 0; q < 8; q++)
            dst[q] = make_float4(h[q*4], h[q*4+1], h[q*4+2], h[q*4+3]);
        float r0 = fea[(size_t)i*11 + 9];
        float r1 = fea[(size_t)i*11 + 10];
        int bb = ind[(size_t)i*3 + 0];
        int gx = ind[(size_t)i*3 + 1];
        int gy = ind[(size_t)i*3 + 2];
        unsigned vox = ((unsigned)bb*GXd + (unsigned)gx)*GYd + (unsigned)gy;
        rank[i] = atomicAdd(&cnt[vox], 1u);
        size_t rbase = (size_t)bb*2*GXY + (size_t)gx*GYd + gy;
        atomicMax(pres + rbase,       mapf(r0));
        atomicMax(pres + rbase + GXY, mapf(r1));
    }
    reduce_stats<32>(h, valid, gsum, gsq);
}

// ---------- layer2 ----------
__global__ __launch_bounds__(256)
void k_l2(const float* __restrict__ z1,
          const float* __restrict__ w2, const float* __restrict__ b2,
          const float* __restrict__ a1, const float* __restrict__ c1,
          float* __restrict__ z2, float* gsum, float* gsq, int n){
    __shared__ float4 w2s[32*16];
    for (int e = threadIdx.x; e < 2048; e += 256) ((float*)w2s)[e] = w2[e];
    __syncthreads();
    int i = blockIdx.x*256 + threadIdx.x;
    bool valid = i < n;
    int i2 = valid ? i : 0;
    float h[32];
    const float4* src = (const float4*)(z1 + (size_t)i2*32);
#pragma unroll
    for (int q = 0; q < 8; q++){
        float4 v = src[q];
        h[q*4+0] = fmaxf(fmaf(v.x, a1[q*4+0], c1[q*4+0]), 0.f);
        h[q*4+1] = fmaxf(fmaf(v.y, a1[q*4+1], c1[q*4+1]), 0.f);
        h[q*4+2] = fmaxf(fmaf(v.z, a1[q*4+2], c1[q*4+2]), 0.f);
        h[q*4+3] = fmaxf(fmaf(v.w, a1[q*4+3], c1[q*4+3]), 0.f);
    }
    float acc[64];
#pragma unroll
    for (int j = 0; j < 64; j++) acc[j] = b2[j];
#pragma unroll
    for (int k = 0; k < 32; k++){
        float v = h[k];
#pragma unroll
        for (int q = 0; q < 16; q++){
            float4 w = w2s[k*16 + q];
            acc[q*4+0] = fmaf(v, w.x, acc[q*4+0]);
            acc[q*4+1] = fmaf(v, w.y, acc[q*4+1]);
            acc[q*4+2] = fmaf(v, w.z, acc[q*4+2]);
            acc[q*4+3] = fmaf(v, w.w, acc[q*4+3]);
        }
    }
    if (valid){
        float4* dst = (float4*)(z2 + (size_t)i*64);
#pragma unroll
        for (int q = 0; q < 16; q++)
            dst[q] = make_float4(acc[q*4], acc[q*4+1], acc[q*4+2], acc[q*4+3]);
    }
    reduce_stats<64>(acc, valid, gsum, gsq);
}

// ---------- layer3: z3 bf16; stats from rounded values; cb loop PINNED ----------
__global__ __launch_bounds__(256)
void k_l3(const float* __restrict__ z2,
          const float* __restrict__ w3, const float* __restrict__ b3,
          const float* __restrict__ a2, const float* __restrict__ c2,
          unsigned short* __restrict__ z3, float* gsum, float* gsq, int n){
    __shared__ float4 w3s[64*32];
    for (int e = threadIdx.x; e < 8192; e += 256) ((float*)w3s)[e] = w3[e];
    __syncthreads();
    int i = blockIdx.x*256 + threadIdx.x;
    bool valid = i < n;
    int i2 = valid ? i : 0;
    float h[64];
    const float4* src = (const float4*)(z2 + (size_t)i2*64);
#pragma unroll
    for (int q = 0; q < 16; q++){
        float4 v = src[q];
        h[q*4+0] = fmaxf(fmaf(v.x, a2[q*4+0], c2[q*4+0]), 0.f);
        h[q*4+1] = fmaxf(fmaf(v.y, a2[q*4+1], c2[q*4+1]), 0.f);
        h[q*4+2] = fmaxf(fmaf(v.z, a2[q*4+2], c2[q*4+2]), 0.f);
        h[q*4+3] = fmaxf(fmaf(v.w, a2[q*4+3], c2[q*4+3]), 0.f);
    }
#pragma unroll 1
    for (int cb = 0; cb < 128; cb += 32){
        float acc[32];
#pragma unroll
        for (int cc = 0; cc < 32; cc++) acc[cc] = b3[cb + cc];
#pragma unroll
        for (int k = 0; k < 64; k++){
            float v = h[k];
#pragma unroll
            for (int q = 0; q < 8; q++){
                float4 w = w3s[k*32 + (cb >> 2) + q];
                acc[q*4+0] = fmaf(v, w.x, acc[q*4+0]);
                acc[q*4+1] = fmaf(v, w.y, acc[q*4+1]);
                acc[q*4+2] = fmaf(v, w.z, acc[q*4+2]);
                acc[q*4+3] = fmaf(v, w.w, acc[q*4+3]);
            }
        }
        unsigned ob[16];
#pragma unroll
        for (int m = 0; m < 16; m++){
            unsigned short lo = f2bf(acc[2*m]);
            unsigned short hi = f2bf(acc[2*m+1]);
            ob[m] = (unsigned)lo | ((unsigned)hi << 16);
            acc[2*m]   = bf2f(lo);          // reuse acc for rounded values
            acc[2*m+1] = bf2f(hi);
        }
        if (valid){
            uint4* dst = (uint4*)(z3 + (size_t)i*128 + cb);
#pragma unroll
            for (int q = 0; q < 4; q++)
                dst[q] = make_uint4(ob[q*4], ob[q*4+1], ob[q*4+2], ob[q*4+3]);
        }
        reduce_stats<32>(acc, valid, gsum + cb, gsq + cb);
    }
}

// ---------- exclusive scan of cnt via block tickets ----------
__global__ __launch_bounds__(256)
void k_off(const unsigned* __restrict__ cnt, unsigned* __restrict__ off,
           unsigned* __restrict__ gctr){
    __shared__ unsigned wtot[4];
    __shared__ unsigned wbase[4];
    int t = threadIdx.x;
    int lane = t & 63, w = t >> 6;
    int base = blockIdx.x * 1024 + t * 4;
    bool ok = base < NCELL;
    unsigned c0 = 0, c1 = 0, c2 = 0, c3 = 0;
    if (ok){ c0 = cnt[base]; c1 = cnt[base+1]; c2 = cnt[base+2]; c3 = cnt[base+3]; }
    unsigned tot = c0 + c1 + c2 + c3;
    unsigned incl = tot;
#pragma unroll
    for (int o = 1; o < 64; o <<= 1){
        unsigned v = __shfl_up(incl, o, 64);
        if (lane >= o) incl += v;
    }
    if (lane == 63) wtot[w] = incl;
    __syncthreads();
    if (t == 0){
        unsigned bt = wtot[0] + wtot[1] + wtot[2] + wtot[3];
        unsigned gb = atomicAdd(gctr, bt);
        unsigned s = 0;
#pragma unroll
        for (int q = 0; q < 4; q++){ wbase[q] = gb + s; s += wtot[q]; }
    }
    __syncthreads();
    if (ok){
        unsigned tb = wbase[w] + incl - tot;
        off[base]   = tb;
        off[base+1] = tb + c0;
        off[base+2] = tb + c0 + c1;
        off[base+3] = tb + c0 + c1 + c2;
    }
}

// ---------- fill per-cell point lists ----------
__global__ __launch_bounds__(256)
void k_fill(const int* __restrict__ ind, const unsigned* __restrict__ rank,
            const unsigned* __restrict__ off, unsigned* __restrict__ list, int n){
    int i = blockIdx.x*256 + threadIdx.x;
    if (i >= n) return;
    int bb = ind[(size_t)i*3], gx = ind[(size_t)i*3+1], gy = ind[(size_t)i*3+2];
    unsigned vox = ((unsigned)bb*GXd + (unsigned)gx)*GYd + (unsigned)gy;
    list[off[vox] + rank[i]] = (unsigned)i;
}

// ---------- layer4 via MFMA: C[n x 256] = bn3relu(z3)[n x 128] @ w4 ----------
__global__ __launch_bounds__(256)
void k_l4(const unsigned short* __restrict__ z3,
          const float* __restrict__ w4, const float* __restrict__ b4,
          const float* __restrict__ a3, const float* __restrict__ c3,
          unsigned short* __restrict__ z4, int n){
    __shared__ short w4t[256*128];           // 64 KB: bf16 w4^T [c][k], swizzled
    int tid = threadIdx.x;
    for (int e = tid; e < 16384; e += 256){  // k-pairs; global reads coalesced
        int k2 = e >> 8;                     // 0..63
        int c  = e & 255;
        unsigned lo = f2bf(w4[(size_t)(2*k2)*256 + c]);
        unsigned hi = f2bf(w4[(size_t)(2*k2+1)*256 + c]);
        int addr = (c*256 + k2*4) ^ ((c & 7) << 4);
        *(unsigned*)((char*)w4t + addr) = lo | (hi << 16);
    }
    __syncthreads();

    int lane = tid & 63, wid = tid >> 6;
    int l15 = lane & 15, lg = lane >> 4;
    int p0 = blockIdx.x*64 + wid*16;
    int prow = p0 + l15;
    int prow2 = prow < n ? prow : (n - 1);
    const unsigned short* zrow = z3 + (size_t)prow2*128;

    f32x4 acc[16];
#pragma unroll
    for (int t = 0; t < 16; t++){
        float bv = b4[t*16 + l15];
        acc[t] = (f32x4){bv, bv, bv, bv};
    }

#pragma unroll
    for (int ks = 0; ks < 4; ks++){
        int kbase = ks*32 + lg*8;
        uint4 ua = *(const uint4*)(zrow + kbase);
        float4 av0 = *(const float4*)(a3 + kbase);
        float4 av1 = *(const float4*)(a3 + kbase + 4);
        float4 cv0 = *(const float4*)(c3 + kbase);
        float4 cv1 = *(const float4*)(c3 + kbase + 4);
        bf16x8 af;
        af[0] = (short)f2bf(fmaxf(fmaf(bf2f((unsigned short)(ua.x & 0xFFFFu)), av0.x, cv0.x), 0.f));
        af[1] = (short)f2bf(fmaxf(fmaf(bf2f((unsigned short)(ua.x >> 16)),     av0.y, cv0.y), 0.f));
        af[2] = (short)f2bf(fmaxf(fmaf(bf2f((unsigned short)(ua.y & 0xFFFFu)), av0.z, cv0.z), 0.f));
        af[3] = (short)f2bf(fmaxf(fmaf(bf2f((unsigned short)(ua.y >> 16)),     av0.w, cv0.w), 0.f));
        af[4] = (short)f2bf(fmaxf(fmaf(bf2f((unsigned short)(ua.z & 0xFFFFu)), av1.x, cv1.x), 0.f));
        af[5] = (short)f2bf(fmaxf(fmaf(bf2f((unsigned short)(ua.z >> 16)),     av1.y, cv1.y), 0.f));
        af[6] = (short)f2bf(fmaxf(fmaf(bf2f((unsigned short)(ua.w & 0xFFFFu)), av1.z, cv1.z), 0.f));
        af[7] = (short)f2bf(fmaxf(fmaf(bf2f((unsigned short)(ua.w >> 16)),     av1.w, cv1.w), 0.f));
#pragma unroll
        for (int t = 0; t < 16; t++){
            int c = t*16 + l15;
            int addr = (c*256 + kbase*2) ^ ((c & 7) << 4);
            bf16x8 bf = *(const bf16x8*)((const char*)w4t + addr);
            acc[t] = __builtin_amdgcn_mfma_f32_16x16x32_bf16(af, bf, acc[t], 0, 0, 0);
        }
    }

#pragma unroll
    for (int t = 0; t < 16; t++){
#pragma unroll
        for (int r = 0; r < 4; r++){
            int pr = p0 + lg*4 + r;
            if (pr < n)
                z4[(size_t)pr*256 + t*16 + l15] = f2bf(acc[t][r]);
        }
    }
}

// ---------- gather-max: one wave per cell, 4 channels per lane ----------
__global__ __launch_bounds__(256)
void k_gather(const unsigned* __restrict__ cnt, const unsigned* __restrict__ off,
              const unsigned* __restrict__ list,
              const unsigned short* __restrict__ z4,
              unsigned short* __restrict__ pooled){
    int lane = threadIdx.x & 63;
    int wid  = blockIdx.x*4 + (threadIdx.x >> 6);
    int wstride = gridDim.x * 4;
    for (int cell = wid; cell < NCELL; cell += wstride){
        unsigned cn = cnt[cell];
        unsigned o  = off[cell];
        float m0 = -__builtin_inff(), m1 = m0, m2 = m0, m3 = m0;
        for (unsigned p = 0; p < cn; p++){
            unsigned pid = list[o + p];
            uint2 u = *(const uint2*)(z4 + (size_t)pid*256 + lane*4);
            m0 = fmaxf(m0, __uint_as_float(u.x << 16));
            m1 = fmaxf(m1, __uint_as_float(u.x & 0xFFFF0000u));
            m2 = fmaxf(m2, __uint_as_float(u.y << 16));
            m3 = fmaxf(m3, __uint_as_float(u.y & 0xFFFF0000u));
        }
        if (cn == 0){ m0 = m1 = m2 = m3 = 0.f; }
        unsigned p0 = (__float_as_uint(m0) >> 16) | (__float_as_uint(m1) & 0xFFFF0000u);
        unsigned p1 = (__float_as_uint(m2) >> 16) | (__float_as_uint(m3) & 0xFFFF0000u);
        *(uint2*)(pooled + (size_t)cell*256 + lane*4) = make_uint2(p0, p1);
    }
}

// ---------- 3x3 maxpool: 4 gx x 16 gy tile, 2 ch/thread, 2 y-halves; 32 KB LDS ----------
// Phase 1: thread (cpair=t&127, ysub=t>>7) computes rolling 3x3 max for 2 channels
// over 8 output rows (10 input rows), uint (2ch) global reads -> 256 B/wave/instr.
// Phase 2: c=t, float4 planar stores (full-line fills). LDS 32 KB -> 4 blocks/CU.
__global__ __launch_bounds__(256)
void k_maxpool(const unsigned short* __restrict__ pooled, float* __restrict__ out){
    __shared__ unsigned short tile[4*16*256];   // [g][yl][c] bf16 = 32 KB
    int t = threadIdx.x;
    int cpair = t & 127;                        // channels 2*cpair, 2*cpair+1
    int ysub  = t >> 7;                         // 0/1: output rows [ysub*8, ysub*8+8)
    int gy0 = blockIdx.x * 16;
    int gx0 = blockIdx.y * 4;
    int b   = blockIdx.z;
    int ymax = GYd - gy0; if (ymax > 16) ymax = 16;   // 16 or 8
    const unsigned short* base = pooled + (size_t)b*GXY*256 + cpair*2;

    float cA0[4], cA1[4], cB0[4], cB1[4];
#pragma unroll
    for (int g = 0; g < 4; g++){ cA0[g]=cA1[g]=cB0[g]=cB1[g]=0.f; }
    int yb = gy0 + ysub*8;
    for (int tt = 0; tt < 10; tt++){
        int yy = yb - 1 + tt;
        bool yok = (unsigned)yy < (unsigned)GYd;
        float v0[6], v1[6];
#pragma unroll
        for (int r = 0; r < 6; r++){
            int xx = gx0 - 1 + r;
            float u0 = -__builtin_inff(), u1 = u0;
            if (yok && (unsigned)xx < (unsigned)GXd){
                unsigned u = *(const unsigned*)(base + ((size_t)xx*GYd + yy)*256);
                u0 = bf2f((unsigned short)(u & 0xFFFFu));
                u1 = bf2f((unsigned short)(u >> 16));
            }
            v0[r] = u0; v1[r] = u1;
        }
        float cm0[4], cm1[4];
#pragma unroll
        for (int g = 0; g < 4; g++){
            cm0[g] = fmaxf(fmaxf(v0[g], v0[g+1]), v0[g+2]);
            cm1[g] = fmaxf(fmaxf(v1[g], v1[g+1]), v1[g+2]);
        }
        if (tt >= 2){
            int oy = yy - 1;                     // = yb + tt - 2
            int yl = oy - gy0;
            if (yl < ymax){
#pragma unroll
                for (int g = 0; g < 4; g++){
                    float m0 = fmaxf(fmaxf(cA0[g], cB0[g]), cm0[g]);
                    float m1 = fmaxf(fmaxf(cA1[g], cB1[g]), cm1[g]);
                    *(unsigned*)&tile[(g*16 + yl)*256 + cpair*2] =
                        (unsigned)f2bf(m0) | ((unsigned)f2bf(m1) << 16);
                }
            }
        }
#pragma unroll
        for (int g = 0; g < 4; g++){
            cA0[g] = cB0[g]; cB0[g] = cm0[g];
            cA1[g] = cB1[g]; cB1[g] = cm1[g];
        }
    }
    __syncthreads();

    int c = t;                                   // 0..255
#pragma unroll 1
    for (int g = 0; g < 4; g++){
        float* dst = out + ((size_t)b*258 + c)*GXY + (size_t)(gx0+g)*GYd + gy0;
        const unsigned short* srcl = &tile[g*16*256 + c];
#pragma unroll 1
        for (int y = 0; y < ymax; y += 4){
            float4 o4;
            o4.x = bf2f(srcl[(y+0)*256]);
            o4.y = bf2f(srcl[(y+1)*256]);
            o4.z = bf2f(srcl[(y+2)*256]);
            o4.w = bf2f(srcl[(y+3)*256]);
            *(float4*)(dst + y) = o4;
        }
    }
}

// ---------- residual channels ----------
__global__ __launch_bounds__(256)
void k_res(const unsigned* __restrict__ pres, float* __restrict__ out){
    int idx = blockIdx.x*256 + threadIdx.x;
    const int total = NBd*2*GXY;
    if (idx >= total) return;
    int gy = idx % GYd;
    int t  = idx / GYd;
    int gx = t % GXd;  t /= GXd;
    int r  = t & 1;
    int b  = t >> 1;
    unsigned u = pres[idx];
    float f = u ? unmapf(u) : 0.f;
    out[(((size_t)b*258 + 256 + r)*GXd + gx)*GYd + gy] = f;
}

extern "C" void kernel_launch(void* const* d_in, const int* in_sizes, int n_in,
                              void* d_out, int out_size, void* d_ws, size_t ws_size,
                              hipStream_t stream){
    (void)n_in; (void)out_size; (void)ws_size;
    const float* fea   = (const float*)d_in[0];
    const int*   ind   = (const int*)  d_in[1];
    const float* bn0_g = (const float*)d_in[2];
    const float* bn0_b = (const float*)d_in[3];
    const float* w1    = (const float*)d_in[4];
    const float* b1    = (const float*)d_in[5];
    const float* bn1_g = (const float*)d_in[6];
    const float* bn1_b = (const float*)d_in[7];
    const float* w2    = (const float*)d_in[8];
    const float* b2    = (const float*)d_in[9];
    const float* bn2_g = (const float*)d_in[10];
    const float* bn2_b = (const float*)d_in[11];
    const float* w3    = (const float*)d_in[12];
    const float* b3    = (const float*)d_in[13];
    const float* bn3_g = (const float*)d_in[14];
    const float* bn3_b = (const float*)d_in[15];
    const float* w4    = (const float*)d_in[16];
    const float* b4    = (const float*)d_in[17];

    int n = in_sizes[0] / 11;
    float invN = 1.0f / (float)n;

    // ---- ws layout ----
    const size_t Z4_B     = (size_t)240000*256*2;       // 122,880,000
    const size_t POOL_B   = (size_t)NCELL*256*2;        // 176,947,200
    const size_t PRES_B   = (size_t)NBd*2*GXY*4;        //   5,529,600
    const size_t CNT_B    = (size_t)NCELL*4;            //   2,764,800
    const size_t STAT_B   = 960*4;
    const size_t GCTR_B   = 256;

    char* base = (char*)d_ws;
    unsigned short* z4     = (unsigned short*)base;
    unsigned short* pooled = (unsigned short*)(base + Z4_B);
    // z1/z2/z3 alias the pooled region (dead before k_gather writes it)
    float*          z1     = (float*)(base + Z4_B);
    float*          z2     = (float*)(base + Z4_B + 30720000);
    unsigned short* z3     = (unsigned short*)(base + Z4_B + 92160000);
    unsigned* pres  = (unsigned*)(base + Z4_B + POOL_B);
    unsigned* cnt   = (unsigned*)((char*)pres + PRES_B);
    float*    stats = (float*)((char*)cnt + CNT_B);
    unsigned* gctr  = (unsigned*)((char*)stats + STAT_B);
    unsigned* off   = (unsigned*)((char*)gctr + GCTR_B);
    unsigned* list  = (unsigned*)((char*)off + CNT_B);
    unsigned* rank  = (unsigned*)((char*)list + (size_t)240000*4);

    float* sum0 = stats;       float* sq0 = stats + 16;
    float* sum1 = stats + 32;  float* sq1 = stats + 64;
    float* sum2 = stats + 96;  float* sq2 = stats + 160;
    float* sum3 = stats + 224; float* sq3 = stats + 352;
    float* a0 = stats + 480;   float* c0 = stats + 496;
    float* a1 = stats + 512;   float* c1 = stats + 544;
    float* a2 = stats + 576;   float* c2 = stats + 640;
    float* a3 = stats + 704;   float* c3 = stats + 832;

    hipMemsetAsync(pres, 0, PRES_B + CNT_B + STAT_B + GCTR_B, stream);

    int nb = (n + 255) / 256;
    k_stats0<<<nb, 256, 0, stream>>>(fea, sum0, sq0, n);
    k_fin<<<1, 128, 0, stream>>>(sum0, sq0, bn0_g, bn0_b, a0, c0, 9,  invN);
    k_l1<<<nb, 256, 0, stream>>>(fea, ind, w1, b1, a0, c0, z1, pres, cnt, rank, sum1, sq1, n);
    k_fin<<<1, 128, 0, stream>>>(sum1, sq1, bn1_g, bn1_b, a1, c1, 32, invN);
    k_l2<<<nb, 256, 0, stream>>>(z1, w2, b2, a1, c1, z2, sum2, sq2, n);
    k_fin<<<1, 128, 0, stream>>>(sum2, sq2, bn2_g, bn2_b, a2, c2, 64, invN);
    k_l3<<<nb, 256, 0, stream>>>(z2, w3, b3, a2, c2, z3, sum3, sq3, n);
    k_fin<<<1, 128, 0, stream>>>(sum3, sq3, bn3_g, bn3_b, a3, c3, 128, invN);

    k_off <<<(NCELL + 1023)/1024, 256, 0, stream>>>(cnt, off, gctr);
    k_fill<<<nb, 256, 0, stream>>>(ind, rank, off, list, n);

    k_l4<<<(n + 63) / 64, 256, 0, stream>>>(z3, w4, b4, a3, c3, z4, n);

    k_gather<<<2048, 256, 0, stream>>>(cnt, off, list, z4, pooled);

    k_maxpool<<<dim3(23, 120, 2), 256, 0, stream>>>(pooled, (float*)d_out);
    k_res<<<(NBd*2*GXY + 255) / 256, 256, 0, stream>>>(pres, (float*)d_out);
}

// Round 10
// 800.709 us; speedup vs baseline: 51.8888x; 1.4774x over previous
//
#include <hip/hip_runtime.h>
#include <cstdint>
#include <cstddef>

#define GXd 480
#define GYd 360
#define NBd 2
#define GXY (480*360)
#define NCELL (NBd*GXY)
#define EPSBN 1e-5f

typedef float  f32x4  __attribute__((ext_vector_type(4)));
typedef short  bf16x8 __attribute__((ext_vector_type(8)));

// ---------- order-preserving float <-> uint map (residual atomics only) ----------
__device__ __forceinline__ unsigned mapf(float f){
    unsigned u = __float_as_uint(f);
    return (u & 0x80000000u) ? ~u : (u | 0x80000000u);
}
__device__ __forceinline__ float unmapf(unsigned m){
    return (m & 0x80000000u) ? __uint_as_float(m ^ 0x80000000u)
                             : __uint_as_float(~m);
}

// ---------- bf16 helpers (RTN-even) ----------
__device__ __forceinline__ unsigned short f2bf(float f){
    unsigned u = __float_as_uint(f);
    unsigned r = (u + 0x7FFFu + ((u >> 16) & 1u)) >> 16;
    return (unsigned short)r;
}
__device__ __forceinline__ float bf2f(unsigned short s){
    return __uint_as_float(((unsigned)s) << 16);
}

// ---------- dense layer helper ----------
template<int DIN, int DOUT>
__device__ __forceinline__ void dense(const float (&in)[DIN], float (&out)[DOUT],
                                      const float* __restrict__ w,
                                      const float* __restrict__ b){
#pragma unroll
    for (int j = 0; j < DOUT; j++) out[j] = b[j];
#pragma unroll
    for (int d = 0; d < DIN; d++){
        float v = in[d];
#pragma unroll
        for (int j = 0; j < DOUT; j++) out[j] = fmaf(v, w[d*DOUT + j], out[j]);
    }
}

// ---------- block-level sum/sumsq reduction ----------
template<int D>
__device__ __forceinline__ void reduce_stats(const float (&h)[D], bool valid,
                                             float* __restrict__ gsum,
                                             float* __restrict__ gsq){
    __shared__ float ssum[D];
    __shared__ float ssq[D];
    int tid = threadIdx.x;
    for (int t = tid; t < D; t += 256){ ssum[t] = 0.f; ssq[t] = 0.f; }
    __syncthreads();
#pragma unroll
    for (int j = 0; j < D; j++){
        float v = valid ? h[j] : 0.f;
        float s = v * v;
#pragma unroll
        for (int o = 32; o > 0; o >>= 1){
            v += __shfl_down(v, o, 64);
            s += __shfl_down(s, o, 64);
        }
        if ((tid & 63) == 0){
            atomicAdd(&ssum[j], v);
            atomicAdd(&ssq[j], s);
        }
    }
    __syncthreads();
    for (int t = tid; t < D; t += 256){
        atomicAdd(&gsum[t], ssum[t]);
        atomicAdd(&gsq[t], ssq[t]);
    }
}

// ---------- stats of raw input columns 0..8 ----------
__global__ __launch_bounds__(256)
void k_stats0(const float* __restrict__ fea, float* gsum, float* gsq, int n){
    int i = blockIdx.x*256 + threadIdx.x;
    bool valid = i < n;
    int i2 = valid ? i : 0;
    float x[9];
#pragma unroll
    for (int d = 0; d < 9; d++) x[d] = fea[(size_t)i2*11 + d];
    reduce_stats<9>(x, valid, gsum, gsq);
}

// ---------- finalize BN ----------
__global__ void k_fin(const float* __restrict__ sum, const float* __restrict__ sq,
                      const float* __restrict__ g, const float* __restrict__ bb,
                      float* __restrict__ a_out, float* __restrict__ c_out,
                      int D, float invN){
    int t = threadIdx.x;
    if (t < D){
        float mu  = sum[t] * invN;
        float var = fmaf(-mu, mu, sq[t] * invN);
        float rs  = rsqrtf(var + EPSBN);
        float a   = rs * g[t];
        a_out[t] = a;
        c_out[t] = fmaf(-mu, a, bb[t]);
    }
}

// ---------- layer1: bn0 -> 9x32; z1; stats; voxel count+rank; res atomics ----------
__global__ __launch_bounds__(256)
void k_l1(const float* __restrict__ fea, const int* __restrict__ ind,
          const float* __restrict__ w1, const float* __restrict__ b1,
          const float* __restrict__ a0, const float* __restrict__ c0,
          float* __restrict__ z1, unsigned* __restrict__ pres,
          unsigned* __restrict__ cnt, unsigned* __restrict__ rank,
          float* gsum, float* gsq, int n){
    int i = blockIdx.x*256 + threadIdx.x;
    bool valid = i < n;
    int i2 = valid ? i : 0;
    float x[9];
#pragma unroll
    for (int d = 0; d < 9; d++) x[d] = fmaf(fea[(size_t)i2*11 + d], a0[d], c0[d]);
    float h[32];
    dense<9,32>(x, h, w1, b1);
    if (valid){
        float4* dst = (float4*)(z1 + (size_t)i*32);
#pragma unroll
        for (int q = 0; q < 8; q++)
            dst[q] = make_float4(h[q*4], h[q*4+1], h[q*4+2], h[q*4+3]);
        float r0 = fea[(size_t)i*11 + 9];
        float r1 = fea[(size_t)i*11 + 10];
        int bb = ind[(size_t)i*3 + 0];
        int gx = ind[(size_t)i*3 + 1];
        int gy = ind[(size_t)i*3 + 2];
        unsigned vox = ((unsigned)bb*GXd + (unsigned)gx)*GYd + (unsigned)gy;
        rank[i] = atomicAdd(&cnt[vox], 1u);
        size_t rbase = (size_t)bb*2*GXY + (size_t)gx*GYd + gy;
        atomicMax(pres + rbase,       mapf(r0));
        atomicMax(pres + rbase + GXY, mapf(r1));
    }
    reduce_stats<32>(h, valid, gsum, gsq);
}

// ---------- layer2 via MFMA: z2[n x 64] = bn1relu(z1)[n x 32] @ w2 ----------
// wave: 16 points x 64 ch; w2 bf16 [c][k] LDS, row stride 40 shorts (2-way banks).
__global__ __launch_bounds__(256)
void k_l2(const float* __restrict__ z1,
          const float* __restrict__ w2, const float* __restrict__ b2,
          const float* __restrict__ a1, const float* __restrict__ c1,
          float* __restrict__ z2, float* gsum, float* gsq, int n){
    __shared__ short w2t[64*40];             // 5120 B
    __shared__ float ssum[64], ssq[64];
    int tid = threadIdx.x;
    if (tid < 64){ ssum[tid] = 0.f; ssq[tid] = 0.f; }
    for (int e = tid; e < 2048; e += 256){   // 32k x 64c, coalesced on c
        int k = e >> 6, c = e & 63;
        w2t[c*40 + k] = (short)f2bf(w2[k*64 + c]);
    }
    __syncthreads();

    int lane = tid & 63, wid = tid >> 6;
    int l15 = lane & 15, lg = lane >> 4;
    int p0 = blockIdx.x*64 + wid*16;
    int prow = p0 + l15;
    int prow2 = prow < n ? prow : (n - 1);
    const float* zrow = z1 + (size_t)prow2*32;

    int kbase = lg*8;
    float4 v0 = *(const float4*)(zrow + kbase);
    float4 v1 = *(const float4*)(zrow + kbase + 4);
    float4 av0 = *(const float4*)(a1 + kbase);
    float4 av1 = *(const float4*)(a1 + kbase + 4);
    float4 cv0 = *(const float4*)(c1 + kbase);
    float4 cv1 = *(const float4*)(c1 + kbase + 4);
    bf16x8 af;
    af[0] = (short)f2bf(fmaxf(fmaf(v0.x, av0.x, cv0.x), 0.f));
    af[1] = (short)f2bf(fmaxf(fmaf(v0.y, av0.y, cv0.y), 0.f));
    af[2] = (short)f2bf(fmaxf(fmaf(v0.z, av0.z, cv0.z), 0.f));
    af[3] = (short)f2bf(fmaxf(fmaf(v0.w, av0.w, cv0.w), 0.f));
    af[4] = (short)f2bf(fmaxf(fmaf(v1.x, av1.x, cv1.x), 0.f));
    af[5] = (short)f2bf(fmaxf(fmaf(v1.y, av1.y, cv1.y), 0.f));
    af[6] = (short)f2bf(fmaxf(fmaf(v1.z, av1.z, cv1.z), 0.f));
    af[7] = (short)f2bf(fmaxf(fmaf(v1.w, av1.w, cv1.w), 0.f));

    f32x4 acc[4];
#pragma unroll
    for (int t = 0; t < 4; t++){
        float bv = b2[t*16 + l15];
        acc[t] = (f32x4){bv, bv, bv, bv};
    }
#pragma unroll
    for (int t = 0; t < 4; t++){
        bf16x8 bf = *(const bf16x8*)&w2t[(t*16 + l15)*40 + kbase];
        acc[t] = __builtin_amdgcn_mfma_f32_16x16x32_bf16(af, bf, acc[t], 0, 0, 0);
    }

#pragma unroll
    for (int t = 0; t < 4; t++){
        int c = t*16 + l15;
        float s = 0.f, q = 0.f;
#pragma unroll
        for (int r = 0; r < 4; r++){
            int pr = p0 + lg*4 + r;
            float v = acc[t][r];
            if (pr < n){
                z2[(size_t)pr*64 + c] = v;
                s += v; q += v*v;
            }
        }
        s += __shfl_xor(s, 16, 64);  q += __shfl_xor(q, 16, 64);
        s += __shfl_xor(s, 32, 64);  q += __shfl_xor(q, 32, 64);
        if (lg == 0){ atomicAdd(&ssum[c], s); atomicAdd(&ssq[c], q); }
    }
    __syncthreads();
    if (tid < 64){ atomicAdd(gsum + tid, ssum[tid]); atomicAdd(gsq + tid, ssq[tid]); }
}

// ---------- layer3 via MFMA: z3[n x 128] = bn2relu(z2)[n x 64] @ w3 (bf16 out) ----------
__global__ __launch_bounds__(256)
void k_l3(const float* __restrict__ z2,
          const float* __restrict__ w3, const float* __restrict__ b3,
          const float* __restrict__ a2, const float* __restrict__ c2,
          unsigned short* __restrict__ z3, float* gsum, float* gsq, int n){
    __shared__ short w3t[128*72];            // 18432 B, [c][k] stride 72
    __shared__ float ssum[128], ssq[128];
    int tid = threadIdx.x;
    if (tid < 128){ ssum[tid] = 0.f; ssq[tid] = 0.f; }
    for (int e = tid; e < 8192; e += 256){   // 64k x 128c, coalesced on c
        int k = e >> 7, c = e & 127;
        w3t[c*72 + k] = (short)f2bf(w3[k*128 + c]);
    }
    __syncthreads();

    int lane = tid & 63, wid = tid >> 6;
    int l15 = lane & 15, lg = lane >> 4;
    int p0 = blockIdx.x*64 + wid*16;
    int prow = p0 + l15;
    int prow2 = prow < n ? prow : (n - 1);
    const float* zrow = z2 + (size_t)prow2*64;

    f32x4 acc[8];
#pragma unroll
    for (int t = 0; t < 8; t++){
        float bv = b3[t*16 + l15];
        acc[t] = (f32x4){bv, bv, bv, bv};
    }

#pragma unroll
    for (int ks = 0; ks < 2; ks++){
        int kbase = ks*32 + lg*8;
        float4 v0 = *(const float4*)(zrow + kbase);
        float4 v1 = *(const float4*)(zrow + kbase + 4);
        float4 av0 = *(const float4*)(a2 + kbase);
        float4 av1 = *(const float4*)(a2 + kbase + 4);
        float4 cv0 = *(const float4*)(c2 + kbase);
        float4 cv1 = *(const float4*)(c2 + kbase + 4);
        bf16x8 af;
        af[0] = (short)f2bf(fmaxf(fmaf(v0.x, av0.x, cv0.x), 0.f));
        af[1] = (short)f2bf(fmaxf(fmaf(v0.y, av0.y, cv0.y), 0.f));
        af[2] = (short)f2bf(fmaxf(fmaf(v0.z, av0.z, cv0.z), 0.f));
        af[3] = (short)f2bf(fmaxf(fmaf(v0.w, av0.w, cv0.w), 0.f));
        af[4] = (short)f2bf(fmaxf(fmaf(v1.x, av1.x, cv1.x), 0.f));
        af[5] = (short)f2bf(fmaxf(fmaf(v1.y, av1.y, cv1.y), 0.f));
        af[6] = (short)f2bf(fmaxf(fmaf(v1.z, av1.z, cv1.z), 0.f));
        af[7] = (short)f2bf(fmaxf(fmaf(v1.w, av1.w, cv1.w), 0.f));
#pragma unroll
        for (int t = 0; t < 8; t++){
            bf16x8 bf = *(const bf16x8*)&w3t[(t*16 + l15)*72 + kbase];
            acc[t] = __builtin_amdgcn_mfma_f32_16x16x32_bf16(af, bf, acc[t], 0, 0, 0);
        }
    }

#pragma unroll
    for (int t = 0; t < 8; t++){
        int c = t*16 + l15;
        float s = 0.f, q = 0.f;
#pragma unroll
        for (int r = 0; r < 4; r++){
            int pr = p0 + lg*4 + r;
            unsigned short rb = f2bf(acc[t][r]);
            float rv = bf2f(rb);
            if (pr < n){
                z3[(size_t)pr*128 + c] = rb;
                s += rv; q += rv*rv;
            }
        }
        s += __shfl_xor(s, 16, 64);  q += __shfl_xor(q, 16, 64);
        s += __shfl_xor(s, 32, 64);  q += __shfl_xor(q, 32, 64);
        if (lg == 0){ atomicAdd(&ssum[c], s); atomicAdd(&ssq[c], q); }
    }
    __syncthreads();
    if (tid < 128){ atomicAdd(gsum + tid, ssum[tid]); atomicAdd(gsq + tid, ssq[tid]); }
}

// ---------- exclusive scan of cnt via block tickets ----------
__global__ __launch_bounds__(256)
void k_off(const unsigned* __restrict__ cnt, unsigned* __restrict__ off,
           unsigned* __restrict__ gctr){
    __shared__ unsigned wtot[4];
    __shared__ unsigned wbase[4];
    int t = threadIdx.x;
    int lane = t & 63, w = t >> 6;
    int base = blockIdx.x * 1024 + t * 4;
    bool ok = base < NCELL;
    unsigned c0 = 0, c1 = 0, c2 = 0, c3 = 0;
    if (ok){ c0 = cnt[base]; c1 = cnt[base+1]; c2 = cnt[base+2]; c3 = cnt[base+3]; }
    unsigned tot = c0 + c1 + c2 + c3;
    unsigned incl = tot;
#pragma unroll
    for (int o = 1; o < 64; o <<= 1){
        unsigned v = __shfl_up(incl, o, 64);
        if (lane >= o) incl += v;
    }
    if (lane == 63) wtot[w] = incl;
    __syncthreads();
    if (t == 0){
        unsigned bt = wtot[0] + wtot[1] + wtot[2] + wtot[3];
        unsigned gb = atomicAdd(gctr, bt);
        unsigned s = 0;
#pragma unroll
        for (int q = 0; q < 4; q++){ wbase[q] = gb + s; s += wtot[q]; }
    }
    __syncthreads();
    if (ok){
        unsigned tb = wbase[w] + incl - tot;
        off[base]   = tb;
        off[base+1] = tb + c0;
        off[base+2] = tb + c0 + c1;
        off[base+3] = tb + c0 + c1 + c2;
    }
}

// ---------- fill per-cell point lists ----------
__global__ __launch_bounds__(256)
void k_fill(const int* __restrict__ ind, const unsigned* __restrict__ rank,
            const unsigned* __restrict__ off, unsigned* __restrict__ list, int n){
    int i = blockIdx.x*256 + threadIdx.x;
    if (i >= n) return;
    int bb = ind[(size_t)i*3], gx = ind[(size_t)i*3+1], gy = ind[(size_t)i*3+2];
    unsigned vox = ((unsigned)bb*GXd + (unsigned)gx)*GYd + (unsigned)gy;
    list[off[vox] + rank[i]] = (unsigned)i;
}

// ---------- layer4 via MFMA: C[n x 256] = bn3relu(z3)[n x 128] @ w4 ----------
__global__ __launch_bounds__(256)
void k_l4(const unsigned short* __restrict__ z3,
          const float* __restrict__ w4, const float* __restrict__ b4,
          const float* __restrict__ a3, const float* __restrict__ c3,
          unsigned short* __restrict__ z4, int n){
    __shared__ short w4t[256*128];           // 64 KB: bf16 w4^T [c][k], swizzled
    int tid = threadIdx.x;
    for (int e = tid; e < 16384; e += 256){  // k-pairs; global reads coalesced
        int k2 = e >> 8;                     // 0..63
        int c  = e & 255;
        unsigned lo = f2bf(w4[(size_t)(2*k2)*256 + c]);
        unsigned hi = f2bf(w4[(size_t)(2*k2+1)*256 + c]);
        int addr = (c*256 + k2*4) ^ ((c & 7) << 4);
        *(unsigned*)((char*)w4t + addr) = lo | (hi << 16);
    }
    __syncthreads();

    int lane = tid & 63, wid = tid >> 6;
    int l15 = lane & 15, lg = lane >> 4;
    int p0 = blockIdx.x*64 + wid*16;
    int prow = p0 + l15;
    int prow2 = prow < n ? prow : (n - 1);
    const unsigned short* zrow = z3 + (size_t)prow2*128;

    f32x4 acc[16];
#pragma unroll
    for (int t = 0; t < 16; t++){
        float bv = b4[t*16 + l15];
        acc[t] = (f32x4){bv, bv, bv, bv};
    }

#pragma unroll
    for (int ks = 0; ks < 4; ks++){
        int kbase = ks*32 + lg*8;
        uint4 ua = *(const uint4*)(zrow + kbase);
        float4 av0 = *(const float4*)(a3 + kbase);
        float4 av1 = *(const float4*)(a3 + kbase + 4);
        float4 cv0 = *(const float4*)(c3 + kbase);
        float4 cv1 = *(const float4*)(c3 + kbase + 4);
        bf16x8 af;
        af[0] = (short)f2bf(fmaxf(fmaf(bf2f((unsigned short)(ua.x & 0xFFFFu)), av0.x, cv0.x), 0.f));
        af[1] = (short)f2bf(fmaxf(fmaf(bf2f((unsigned short)(ua.x >> 16)),     av0.y, cv0.y), 0.f));
        af[2] = (short)f2bf(fmaxf(fmaf(bf2f((unsigned short)(ua.y & 0xFFFFu)), av0.z, cv0.z), 0.f));
        af[3] = (short)f2bf(fmaxf(fmaf(bf2f((unsigned short)(ua.y >> 16)),     av0.w, cv0.w), 0.f));
        af[4] = (short)f2bf(fmaxf(fmaf(bf2f((unsigned short)(ua.z & 0xFFFFu)), av1.x, cv1.x), 0.f));
        af[5] = (short)f2bf(fmaxf(fmaf(bf2f((unsigned short)(ua.z >> 16)),     av1.y, cv1.y), 0.f));
        af[6] = (short)f2bf(fmaxf(fmaf(bf2f((unsigned short)(ua.w & 0xFFFFu)), av1.z, cv1.z), 0.f));
        af[7] = (short)f2bf(fmaxf(fmaf(bf2f((unsigned short)(ua.w >> 16)),     av1.w, cv1.w), 0.f));
#pragma unroll
        for (int t = 0; t < 16; t++){
            int c = t*16 + l15;
            int addr = (c*256 + kbase*2) ^ ((c & 7) << 4);
            bf16x8 bf = *(const bf16x8*)((const char*)w4t + addr);
            acc[t] = __builtin_amdgcn_mfma_f32_16x16x32_bf16(af, bf, acc[t], 0, 0, 0);
        }
    }

#pragma unroll
    for (int t = 0; t < 16; t++){
#pragma unroll
        for (int r = 0; r < 4; r++){
            int pr = p0 + lg*4 + r;
            if (pr < n)
                z4[(size_t)pr*256 + t*16 + l15] = f2bf(acc[t][r]);
        }
    }
}

// ---------- gather-max: one wave per cell, 4 channels per lane ----------
__global__ __launch_bounds__(256)
void k_gather(const unsigned* __restrict__ cnt, const unsigned* __restrict__ off,
              const unsigned* __restrict__ list,
              const unsigned short* __restrict__ z4,
              unsigned short* __restrict__ pooled){
    int lane = threadIdx.x & 63;
    int wid  = blockIdx.x*4 + (threadIdx.x >> 6);
    int wstride = gridDim.x * 4;
    for (int cell = wid; cell < NCELL; cell += wstride){
        unsigned cn = cnt[cell];
        unsigned o  = off[cell];
        float m0 = -__builtin_inff(), m1 = m0, m2 = m0, m3 = m0;
        for (unsigned p = 0; p < cn; p++){
            unsigned pid = list[o + p];
            uint2 u = *(const uint2*)(z4 + (size_t)pid*256 + lane*4);
            m0 = fmaxf(m0, __uint_as_float(u.x << 16));
            m1 = fmaxf(m1, __uint_as_float(u.x & 0xFFFF0000u));
            m2 = fmaxf(m2, __uint_as_float(u.y << 16));
            m3 = fmaxf(m3, __uint_as_float(u.y & 0xFFFF0000u));
        }
        if (cn == 0){ m0 = m1 = m2 = m3 = 0.f; }
        unsigned p0 = (__float_as_uint(m0) >> 16) | (__float_as_uint(m1) & 0xFFFF0000u);
        unsigned p1 = (__float_as_uint(m2) >> 16) | (__float_as_uint(m3) & 0xFFFF0000u);
        *(uint2*)(pooled + (size_t)cell*256 + lane*4) = make_uint2(p0, p1);
    }
}

// ---------- 3x3 maxpool: 4 gx x 16 gy tile, 2 ch/thread, 2 y-halves; 32 KB LDS ----------
__global__ __launch_bounds__(256)
void k_maxpool(const unsigned short* __restrict__ pooled, float* __restrict__ out){
    __shared__ unsigned short tile[4*16*256];   // [g][yl][c] bf16 = 32 KB
    int t = threadIdx.x;
    int cpair = t & 127;
    int ysub  = t >> 7;
    int gy0 = blockIdx.x * 16;
    int gx0 = blockIdx.y * 4;
    int b   = blockIdx.z;
    int ymax = GYd - gy0; if (ymax > 16) ymax = 16;
    const unsigned short* base = pooled + (size_t)b*GXY*256 + cpair*2;

    float cA0[4], cA1[4], cB0[4], cB1[4];
#pragma unroll
    for (int g = 0; g < 4; g++){ cA0[g]=cA1[g]=cB0[g]=cB1[g]=0.f; }
    int yb = gy0 + ysub*8;
    for (int tt = 0; tt < 10; tt++){
        int yy = yb - 1 + tt;
        bool yok = (unsigned)yy < (unsigned)GYd;
        float v0[6], v1[6];
#pragma unroll
        for (int r = 0; r < 6; r++){
            int xx = gx0 - 1 + r;
            float u0 = -__builtin_inff(), u1 = u0;
            if (yok && (unsigned)xx < (unsigned)GXd){
                unsigned u = *(const unsigned*)(base + ((size_t)xx*GYd + yy)*256);
                u0 = bf2f((unsigned short)(u & 0xFFFFu));
                u1 = bf2f((unsigned short)(u >> 16));
            }
            v0[r] = u0; v1[r] = u1;
        }
        float cm0[4], cm1[4];
#pragma unroll
        for (int g = 0; g < 4; g++){
            cm0[g] = fmaxf(fmaxf(v0[g], v0[g+1]), v0[g+2]);
            cm1[g] = fmaxf(fmaxf(v1[g], v1[g+1]), v1[g+2]);
        }
        if (tt >= 2){
            int oy = yy - 1;
            int yl = oy - gy0;
            if (yl < ymax){
#pragma unroll
                for (int g = 0; g < 4; g++){
                    float m0 = fmaxf(fmaxf(cA0[g], cB0[g]), cm0[g]);
                    float m1 = fmaxf(fmaxf(cA1[g], cB1[g]), cm1[g]);
                    *(unsigned*)&tile[(g*16 + yl)*256 + cpair*2] =
                        (unsigned)f2bf(m0) | ((unsigned)f2bf(m1) << 16);
                }
            }
        }
#pragma unroll
        for (int g = 0; g < 4; g++){
            cA0[g] = cB0[g]; cB0[g] = cm0[g];
            cA1[g] = cB1[g]; cB1[g] = cm1[g];
        }
    }
    __syncthreads();

    int c = t;
#pragma unroll 1
    for (int g = 0; g < 4; g++){
        float* dst = out + ((size_t)b*258 + c)*GXY + (size_t)(gx0+g)*GYd + gy0;
        const unsigned short* srcl = &tile[g*16*256 + c];
#pragma unroll 1
        for (int y = 0; y < ymax; y += 4){
            float4 o4;
            o4.x = bf2f(srcl[(y+0)*256]);
            o4.y = bf2f(srcl[(y+1)*256]);
            o4.z = bf2f(srcl[(y+2)*256]);
            o4.w = bf2f(srcl[(y+3)*256]);
            *(float4*)(dst + y) = o4;
        }
    }
}

// ---------- residual channels ----------
__global__ __launch_bounds__(256)
void k_res(const unsigned* __restrict__ pres, float* __restrict__ out){
    int idx = blockIdx.x*256 + threadIdx.x;
    const int total = NBd*2*GXY;
    if (idx >= total) return;
    int gy = idx % GYd;
    int t  = idx / GYd;
    int gx = t % GXd;  t /= GXd;
    int r  = t & 1;
    int b  = t >> 1;
    unsigned u = pres[idx];
    float f = u ? unmapf(u) : 0.f;
    out[(((size_t)b*258 + 256 + r)*GXd + gx)*GYd + gy] = f;
}

extern "C" void kernel_launch(void* const* d_in, const int* in_sizes, int n_in,
                              void* d_out, int out_size, void* d_ws, size_t ws_size,
                              hipStream_t stream){
    (void)n_in; (void)out_size; (void)ws_size;
    const float* fea   = (const float*)d_in[0];
    const int*   ind   = (const int*)  d_in[1];
    const float* bn0_g = (const float*)d_in[2];
    const float* bn0_b = (const float*)d_in[3];
    const float* w1    = (const float*)d_in[4];
    const float* b1    = (const float*)d_in[5];
    const float* bn1_g = (const float*)d_in[6];
    const float* bn1_b = (const float*)d_in[7];
    const float* w2    = (const float*)d_in[8];
    const float* b2    = (const float*)d_in[9];
    const float* bn2_g = (const float*)d_in[10];
    const float* bn2_b = (const float*)d_in[11];
    const float* w3    = (const float*)d_in[12];
    const float* b3    = (const float*)d_in[13];
    const float* bn3_g = (const float*)d_in[14];
    const float* bn3_b = (const float*)d_in[15];
    const float* w4    = (const float*)d_in[16];
    const float* b4    = (const float*)d_in[17];

    int n = in_sizes[0] / 11;
    float invN = 1.0f / (float)n;

    // ---- ws layout ----
    const size_t Z4_B     = (size_t)240000*256*2;       // 122,880,000
    const size_t POOL_B   = (size_t)NCELL*256*2;        // 176,947,200
    const size_t PRES_B   = (size_t)NBd*2*GXY*4;        //   5,529,600
    const size_t CNT_B    = (size_t)NCELL*4;            //   2,764,800
    const size_t STAT_B   = 960*4;
    const size_t GCTR_B   = 256;

    char* base = (char*)d_ws;
    unsigned short* z4     = (unsigned short*)base;
    unsigned short* pooled = (unsigned short*)(base + Z4_B);
    // z1/z2/z3 alias the pooled region (dead before k_gather writes it)
    float*          z1     = (float*)(base + Z4_B);
    float*          z2     = (float*)(base + Z4_B + 30720000);
    unsigned short* z3     = (unsigned short*)(base + Z4_B + 92160000);
    unsigned* pres  = (unsigned*)(base + Z4_B + POOL_B);
    unsigned* cnt   = (unsigned*)((char*)pres + PRES_B);
    float*    stats = (float*)((char*)cnt + CNT_B);
    unsigned* gctr  = (unsigned*)((char*)stats + STAT_B);
    unsigned* off   = (unsigned*)((char*)gctr + GCTR_B);
    unsigned* list  = (unsigned*)((char*)off + CNT_B);
    unsigned* rank  = (unsigned*)((char*)list + (size_t)240000*4);

    float* sum0 = stats;       float* sq0 = stats + 16;
    float* sum1 = stats + 32;  float* sq1 = stats + 64;
    float* sum2 = stats + 96;  float* sq2 = stats + 160;
    float* sum3 = stats + 224; float* sq3 = stats + 352;
    float* a0 = stats + 480;   float* c0 = stats + 496;
    float* a1 = stats + 512;   float* c1 = stats + 544;
    float* a2 = stats + 576;   float* c2 = stats + 640;
    float* a3 = stats + 704;   float* c3 = stats + 832;

    hipMemsetAsync(pres, 0, PRES_B + CNT_B + STAT_B + GCTR_B, stream);

    int nb = (n + 255) / 256;
    int nb64 = (n + 63) / 64;
    k_stats0<<<nb, 256, 0, stream>>>(fea, sum0, sq0, n);
    k_fin<<<1, 128, 0, stream>>>(sum0, sq0, bn0_g, bn0_b, a0, c0, 9,  invN);
    k_l1<<<nb, 256, 0, stream>>>(fea, ind, w1, b1, a0, c0, z1, pres, cnt, rank, sum1, sq1, n);
    k_fin<<<1, 128, 0, stream>>>(sum1, sq1, bn1_g, bn1_b, a1, c1, 32, invN);
    k_l2<<<nb64, 256, 0, stream>>>(z1, w2, b2, a1, c1, z2, sum2, sq2, n);
    k_fin<<<1, 128, 0, stream>>>(sum2, sq2, bn2_g, bn2_b, a2, c2, 64, invN);
    k_l3<<<nb64, 256, 0, stream>>>(z2, w3, b3, a2, c2, z3, sum3, sq3, n);
    k_fin<<<1, 128, 0, stream>>>(sum3, sq3, bn3_g, bn3_b, a3, c3, 128, invN);

    k_off <<<(NCELL + 1023)/1024, 256, 0, stream>>>(cnt, off, gctr);
    k_fill<<<nb, 256, 0, stream>>>(ind, rank, off, list, n);

    k_l4<<<nb64, 256, 0, stream>>>(z3, w4, b4, a3, c3, z4, n);

    k_gather<<<2048, 256, 0, stream>>>(cnt, off, list, z4, pooled);

    k_maxpool<<<dim3(23, 120, 2), 256, 0, stream>>>(pooled, (float*)d_out);
    k_res<<<(NBd*2*GXY + 255) / 256, 256, 0, stream>>>(pres, (float*)d_out);
}

// Round 11
// 742.549 us; speedup vs baseline: 55.9529x; 1.0783x over previous
//
#include <hip/hip_runtime.h>
#include <cstdint>
#include <cstddef>

#define GXd 480
#define GYd 360
#define NBd 2
#define GXY (480*360)
#define NCELL (NBd*GXY)
#define EPSBN 1e-5f

typedef float  f32x4  __attribute__((ext_vector_type(4)));
typedef short  bf16x8 __attribute__((ext_vector_type(8)));

// ---------- order-preserving float <-> uint map (residual atomics only) ----------
__device__ __forceinline__ unsigned mapf(float f){
    unsigned u = __float_as_uint(f);
    return (u & 0x80000000u) ? ~u : (u | 0x80000000u);
}
__device__ __forceinline__ float unmapf(unsigned m){
    return (m & 0x80000000u) ? __uint_as_float(m ^ 0x80000000u)
                             : __uint_as_float(~m);
}

// ---------- bf16 helpers (RTN-even) ----------
__device__ __forceinline__ unsigned short f2bf(float f){
    unsigned u = __float_as_uint(f);
    unsigned r = (u + 0x7FFFu + ((u >> 16) & 1u)) >> 16;
    return (unsigned short)r;
}
__device__ __forceinline__ float bf2f(unsigned short s){
    return __uint_as_float(((unsigned)s) << 16);
}

// ---------- dense layer helper ----------
template<int DIN, int DOUT>
__device__ __forceinline__ void dense(const float (&in)[DIN], float (&out)[DOUT],
                                      const float* __restrict__ w,
                                      const float* __restrict__ b){
#pragma unroll
    for (int j = 0; j < DOUT; j++) out[j] = b[j];
#pragma unroll
    for (int d = 0; d < DIN; d++){
        float v = in[d];
#pragma unroll
        for (int j = 0; j < DOUT; j++) out[j] = fmaf(v, w[d*DOUT + j], out[j]);
    }
}

// ---------- block-level sum/sumsq reduction ----------
template<int D>
__device__ __forceinline__ void reduce_stats(const float (&h)[D], bool valid,
                                             float* __restrict__ gsum,
                                             float* __restrict__ gsq){
    __shared__ float ssum[D];
    __shared__ float ssq[D];
    int tid = threadIdx.x;
    for (int t = tid; t < D; t += 256){ ssum[t] = 0.f; ssq[t] = 0.f; }
    __syncthreads();
#pragma unroll
    for (int j = 0; j < D; j++){
        float v = valid ? h[j] : 0.f;
        float s = v * v;
#pragma unroll
        for (int o = 32; o > 0; o >>= 1){
            v += __shfl_down(v, o, 64);
            s += __shfl_down(s, o, 64);
        }
        if ((tid & 63) == 0){
            atomicAdd(&ssum[j], v);
            atomicAdd(&ssq[j], s);
        }
    }
    __syncthreads();
    for (int t = tid; t < D; t += 256){
        atomicAdd(&gsum[t], ssum[t]);
        atomicAdd(&gsq[t], ssq[t]);
    }
}

// ---------- stats of raw input columns 0..8 ----------
__global__ __launch_bounds__(256)
void k_stats0(const float* __restrict__ fea, float* gsum, float* gsq, int n){
    int i = blockIdx.x*256 + threadIdx.x;
    bool valid = i < n;
    int i2 = valid ? i : 0;
    float x[9];
#pragma unroll
    for (int d = 0; d < 9; d++) x[d] = fea[(size_t)i2*11 + d];
    reduce_stats<9>(x, valid, gsum, gsq);
}

// ---------- finalize BN ----------
__global__ void k_fin(const float* __restrict__ sum, const float* __restrict__ sq,
                      const float* __restrict__ g, const float* __restrict__ bb,
                      float* __restrict__ a_out, float* __restrict__ c_out,
                      int D, float invN){
    int t = threadIdx.x;
    if (t < D){
        float mu  = sum[t] * invN;
        float var = fmaf(-mu, mu, sq[t] * invN);
        float rs  = rsqrtf(var + EPSBN);
        float a   = rs * g[t];
        a_out[t] = a;
        c_out[t] = fmaf(-mu, a, bb[t]);
    }
}

// ---------- layer1: bn0 -> 9x32; z1; stats; voxel count+rank; res atomics ----------
__global__ __launch_bounds__(256)
void k_l1(const float* __restrict__ fea, const int* __restrict__ ind,
          const float* __restrict__ w1, const float* __restrict__ b1,
          const float* __restrict__ a0, const float* __restrict__ c0,
          float* __restrict__ z1, unsigned* __restrict__ pres,
          unsigned* __restrict__ cnt, unsigned* __restrict__ rank,
          float* gsum, float* gsq, int n){
    int i = blockIdx.x*256 + threadIdx.x;
    bool valid = i < n;
    int i2 = valid ? i : 0;
    float x[9];
#pragma unroll
    for (int d = 0; d < 9; d++) x[d] = fmaf(fea[(size_t)i2*11 + d], a0[d], c0[d]);
    float h[32];
    dense<9,32>(x, h, w1, b1);
    if (valid){
        float4* dst = (float4*)(z1 + (size_t)i*32);
#pragma unroll
        for (int q = 0; q < 8; q++)
            dst[q] = make_float4(h[q*4], h[q*4+1], h[q*4+2], h[q*4+3]);
        float r0 = fea[(size_t)i*11 + 9];
        float r1 = fea[(size_t)i*11 + 10];
        int bb = ind[(size_t)i*3 + 0];
        int gx = ind[(size_t)i*3 + 1];
        int gy = ind[(size_t)i*3 + 2];
        unsigned vox = ((unsigned)bb*GXd + (unsigned)gx)*GYd + (unsigned)gy;
        rank[i] = atomicAdd(&cnt[vox], 1u);
        size_t rbase = (size_t)bb*2*GXY + (size_t)gx*GYd + gy;
        atomicMax(pres + rbase,       mapf(r0));
        atomicMax(pres + rbase + GXY, mapf(r1));
    }
    reduce_stats<32>(h, valid, gsum, gsq);
}

// ---------- layer2 via MFMA: z2[n x 64] = bn1relu(z1)[n x 32] @ w2 ----------
__global__ __launch_bounds__(256)
void k_l2(const float* __restrict__ z1,
          const float* __restrict__ w2, const float* __restrict__ b2,
          const float* __restrict__ a1, const float* __restrict__ c1,
          float* __restrict__ z2, float* gsum, float* gsq, int n){
    __shared__ short w2t[64*40];             // 5120 B
    __shared__ float ssum[64], ssq[64];
    int tid = threadIdx.x;
    if (tid < 64){ ssum[tid] = 0.f; ssq[tid] = 0.f; }
    for (int e = tid; e < 2048; e += 256){
        int k = e >> 6, c = e & 63;
        w2t[c*40 + k] = (short)f2bf(w2[k*64 + c]);
    }
    __syncthreads();

    int lane = tid & 63, wid = tid >> 6;
    int l15 = lane & 15, lg = lane >> 4;
    int p0 = blockIdx.x*64 + wid*16;
    int prow = p0 + l15;
    int prow2 = prow < n ? prow : (n - 1);
    const float* zrow = z1 + (size_t)prow2*32;

    int kbase = lg*8;
    float4 v0 = *(const float4*)(zrow + kbase);
    float4 v1 = *(const float4*)(zrow + kbase + 4);
    float4 av0 = *(const float4*)(a1 + kbase);
    float4 av1 = *(const float4*)(a1 + kbase + 4);
    float4 cv0 = *(const float4*)(c1 + kbase);
    float4 cv1 = *(const float4*)(c1 + kbase + 4);
    bf16x8 af;
    af[0] = (short)f2bf(fmaxf(fmaf(v0.x, av0.x, cv0.x), 0.f));
    af[1] = (short)f2bf(fmaxf(fmaf(v0.y, av0.y, cv0.y), 0.f));
    af[2] = (short)f2bf(fmaxf(fmaf(v0.z, av0.z, cv0.z), 0.f));
    af[3] = (short)f2bf(fmaxf(fmaf(v0.w, av0.w, cv0.w), 0.f));
    af[4] = (short)f2bf(fmaxf(fmaf(v1.x, av1.x, cv1.x), 0.f));
    af[5] = (short)f2bf(fmaxf(fmaf(v1.y, av1.y, cv1.y), 0.f));
    af[6] = (short)f2bf(fmaxf(fmaf(v1.z, av1.z, cv1.z), 0.f));
    af[7] = (short)f2bf(fmaxf(fmaf(v1.w, av1.w, cv1.w), 0.f));

    f32x4 acc[4];
#pragma unroll
    for (int t = 0; t < 4; t++){
        float bv = b2[t*16 + l15];
        acc[t] = (f32x4){bv, bv, bv, bv};
    }
#pragma unroll
    for (int t = 0; t < 4; t++){
        bf16x8 bf = *(const bf16x8*)&w2t[(t*16 + l15)*40 + kbase];
        acc[t] = __builtin_amdgcn_mfma_f32_16x16x32_bf16(af, bf, acc[t], 0, 0, 0);
    }

#pragma unroll
    for (int t = 0; t < 4; t++){
        int c = t*16 + l15;
        float s = 0.f, q = 0.f;
#pragma unroll
        for (int r = 0; r < 4; r++){
            int pr = p0 + lg*4 + r;
            float v = acc[t][r];
            if (pr < n){
                z2[(size_t)pr*64 + c] = v;
                s += v; q += v*v;
            }
        }
        s += __shfl_xor(s, 16, 64);  q += __shfl_xor(q, 16, 64);
        s += __shfl_xor(s, 32, 64);  q += __shfl_xor(q, 32, 64);
        if (lg == 0){ atomicAdd(&ssum[c], s); atomicAdd(&ssq[c], q); }
    }
    __syncthreads();
    if (tid < 64){ atomicAdd(gsum + tid, ssum[tid]); atomicAdd(gsq + tid, ssq[tid]); }
}

// ---------- layer3 via MFMA: z3[n x 128] = bn2relu(z2)[n x 64] @ w3 (bf16 out) ----------
__global__ __launch_bounds__(256)
void k_l3(const float* __restrict__ z2,
          const float* __restrict__ w3, const float* __restrict__ b3,
          const float* __restrict__ a2, const float* __restrict__ c2,
          unsigned short* __restrict__ z3, float* gsum, float* gsq, int n){
    __shared__ short w3t[128*72];            // 18432 B, [c][k] stride 72
    __shared__ float ssum[128], ssq[128];
    int tid = threadIdx.x;
    if (tid < 128){ ssum[tid] = 0.f; ssq[tid] = 0.f; }
    for (int e = tid; e < 8192; e += 256){
        int k = e >> 7, c = e & 127;
        w3t[c*72 + k] = (short)f2bf(w3[k*128 + c]);
    }
    __syncthreads();

    int lane = tid & 63, wid = tid >> 6;
    int l15 = lane & 15, lg = lane >> 4;
    int p0 = blockIdx.x*64 + wid*16;
    int prow = p0 + l15;
    int prow2 = prow < n ? prow : (n - 1);
    const float* zrow = z2 + (size_t)prow2*64;

    f32x4 acc[8];
#pragma unroll
    for (int t = 0; t < 8; t++){
        float bv = b3[t*16 + l15];
        acc[t] = (f32x4){bv, bv, bv, bv};
    }

#pragma unroll
    for (int ks = 0; ks < 2; ks++){
        int kbase = ks*32 + lg*8;
        float4 v0 = *(const float4*)(zrow + kbase);
        float4 v1 = *(const float4*)(zrow + kbase + 4);
        float4 av0 = *(const float4*)(a2 + kbase);
        float4 av1 = *(const float4*)(a2 + kbase + 4);
        float4 cv0 = *(const float4*)(c2 + kbase);
        float4 cv1 = *(const float4*)(c2 + kbase + 4);
        bf16x8 af;
        af[0] = (short)f2bf(fmaxf(fmaf(v0.x, av0.x, cv0.x), 0.f));
        af[1] = (short)f2bf(fmaxf(fmaf(v0.y, av0.y, cv0.y), 0.f));
        af[2] = (short)f2bf(fmaxf(fmaf(v0.z, av0.z, cv0.z), 0.f));
        af[3] = (short)f2bf(fmaxf(fmaf(v0.w, av0.w, cv0.w), 0.f));
        af[4] = (short)f2bf(fmaxf(fmaf(v1.x, av1.x, cv1.x), 0.f));
        af[5] = (short)f2bf(fmaxf(fmaf(v1.y, av1.y, cv1.y), 0.f));
        af[6] = (short)f2bf(fmaxf(fmaf(v1.z, av1.z, cv1.z), 0.f));
        af[7] = (short)f2bf(fmaxf(fmaf(v1.w, av1.w, cv1.w), 0.f));
#pragma unroll
        for (int t = 0; t < 8; t++){
            bf16x8 bf = *(const bf16x8*)&w3t[(t*16 + l15)*72 + kbase];
            acc[t] = __builtin_amdgcn_mfma_f32_16x16x32_bf16(af, bf, acc[t], 0, 0, 0);
        }
    }

#pragma unroll
    for (int t = 0; t < 8; t++){
        int c = t*16 + l15;
        float s = 0.f, q = 0.f;
#pragma unroll
        for (int r = 0; r < 4; r++){
            int pr = p0 + lg*4 + r;
            unsigned short rb = f2bf(acc[t][r]);
            float rv = bf2f(rb);
            if (pr < n){
                z3[(size_t)pr*128 + c] = rb;
                s += rv; q += rv*rv;
            }
        }
        s += __shfl_xor(s, 16, 64);  q += __shfl_xor(q, 16, 64);
        s += __shfl_xor(s, 32, 64);  q += __shfl_xor(q, 32, 64);
        if (lg == 0){ atomicAdd(&ssum[c], s); atomicAdd(&ssq[c], q); }
    }
    __syncthreads();
    if (tid < 128){ atomicAdd(gsum + tid, ssum[tid]); atomicAdd(gsq + tid, ssq[tid]); }
}

// ---------- exclusive scan of cnt via block tickets ----------
__global__ __launch_bounds__(256)
void k_off(const unsigned* __restrict__ cnt, unsigned* __restrict__ off,
           unsigned* __restrict__ gctr){
    __shared__ unsigned wtot[4];
    __shared__ unsigned wbase[4];
    int t = threadIdx.x;
    int lane = t & 63, w = t >> 6;
    int base = blockIdx.x * 1024 + t * 4;
    bool ok = base < NCELL;
    unsigned c0 = 0, c1 = 0, c2 = 0, c3 = 0;
    if (ok){ c0 = cnt[base]; c1 = cnt[base+1]; c2 = cnt[base+2]; c3 = cnt[base+3]; }
    unsigned tot = c0 + c1 + c2 + c3;
    unsigned incl = tot;
#pragma unroll
    for (int o = 1; o < 64; o <<= 1){
        unsigned v = __shfl_up(incl, o, 64);
        if (lane >= o) incl += v;
    }
    if (lane == 63) wtot[w] = incl;
    __syncthreads();
    if (t == 0){
        unsigned bt = wtot[0] + wtot[1] + wtot[2] + wtot[3];
        unsigned gb = atomicAdd(gctr, bt);
        unsigned s = 0;
#pragma unroll
        for (int q = 0; q < 4; q++){ wbase[q] = gb + s; s += wtot[q]; }
    }
    __syncthreads();
    if (ok){
        unsigned tb = wbase[w] + incl - tot;
        off[base]   = tb;
        off[base+1] = tb + c0;
        off[base+2] = tb + c0 + c1;
        off[base+3] = tb + c0 + c1 + c2;
    }
}

// ---------- fill per-cell point lists ----------
__global__ __launch_bounds__(256)
void k_fill(const int* __restrict__ ind, const unsigned* __restrict__ rank,
            const unsigned* __restrict__ off, unsigned* __restrict__ list, int n){
    int i = blockIdx.x*256 + threadIdx.x;
    if (i >= n) return;
    int bb = ind[(size_t)i*3], gx = ind[(size_t)i*3+1], gy = ind[(size_t)i*3+2];
    unsigned vox = ((unsigned)bb*GXd + (unsigned)gx)*GYd + (unsigned)gy;
    list[off[vox] + rank[i]] = (unsigned)i;
}

// ---------- layer4 via MFMA, SORTED output: z4[sorted_pos] = bn3relu(z3[list[pos]]) @ w4 ----------
// Writing z4 in cell-grouped order makes k_gather a pure streaming read.
__global__ __launch_bounds__(256)
void k_l4(const unsigned short* __restrict__ z3, const unsigned* __restrict__ list,
          const float* __restrict__ w4, const float* __restrict__ b4,
          const float* __restrict__ a3, const float* __restrict__ c3,
          unsigned short* __restrict__ z4, int n){
    __shared__ short w4t[256*128];           // 64 KB: bf16 w4^T [c][k], swizzled
    int tid = threadIdx.x;
    for (int e = tid; e < 16384; e += 256){
        int k2 = e >> 8;
        int c  = e & 255;
        unsigned lo = f2bf(w4[(size_t)(2*k2)*256 + c]);
        unsigned hi = f2bf(w4[(size_t)(2*k2+1)*256 + c]);
        int addr = (c*256 + k2*4) ^ ((c & 7) << 4);
        *(unsigned*)((char*)w4t + addr) = lo | (hi << 16);
    }
    __syncthreads();

    int lane = tid & 63, wid = tid >> 6;
    int l15 = lane & 15, lg = lane >> 4;
    int p0 = blockIdx.x*64 + wid*16;
    int prow = p0 + l15;
    int prow2 = prow < n ? prow : (n - 1);
    int srow = (int)list[prow2];             // original point id (sorted by cell)
    const unsigned short* zrow = z3 + (size_t)srow*128;

    f32x4 acc[16];
#pragma unroll
    for (int t = 0; t < 16; t++){
        float bv = b4[t*16 + l15];
        acc[t] = (f32x4){bv, bv, bv, bv};
    }

#pragma unroll
    for (int ks = 0; ks < 4; ks++){
        int kbase = ks*32 + lg*8;
        uint4 ua = *(const uint4*)(zrow + kbase);
        float4 av0 = *(const float4*)(a3 + kbase);
        float4 av1 = *(const float4*)(a3 + kbase + 4);
        float4 cv0 = *(const float4*)(c3 + kbase);
        float4 cv1 = *(const float4*)(c3 + kbase + 4);
        bf16x8 af;
        af[0] = (short)f2bf(fmaxf(fmaf(bf2f((unsigned short)(ua.x & 0xFFFFu)), av0.x, cv0.x), 0.f));
        af[1] = (short)f2bf(fmaxf(fmaf(bf2f((unsigned short)(ua.x >> 16)),     av0.y, cv0.y), 0.f));
        af[2] = (short)f2bf(fmaxf(fmaf(bf2f((unsigned short)(ua.y & 0xFFFFu)), av0.z, cv0.z), 0.f));
        af[3] = (short)f2bf(fmaxf(fmaf(bf2f((unsigned short)(ua.y >> 16)),     av0.w, cv0.w), 0.f));
        af[4] = (short)f2bf(fmaxf(fmaf(bf2f((unsigned short)(ua.z & 0xFFFFu)), av1.x, cv1.x), 0.f));
        af[5] = (short)f2bf(fmaxf(fmaf(bf2f((unsigned short)(ua.z >> 16)),     av1.y, cv1.y), 0.f));
        af[6] = (short)f2bf(fmaxf(fmaf(bf2f((unsigned short)(ua.w & 0xFFFFu)), av1.z, cv1.z), 0.f));
        af[7] = (short)f2bf(fmaxf(fmaf(bf2f((unsigned short)(ua.w >> 16)),     av1.w, cv1.w), 0.f));
#pragma unroll
        for (int t = 0; t < 16; t++){
            int c = t*16 + l15;
            int addr = (c*256 + kbase*2) ^ ((c & 7) << 4);
            bf16x8 bf = *(const bf16x8*)((const char*)w4t + addr);
            acc[t] = __builtin_amdgcn_mfma_f32_16x16x32_bf16(af, bf, acc[t], 0, 0, 0);
        }
    }

#pragma unroll
    for (int t = 0; t < 16; t++){
#pragma unroll
        for (int r = 0; r < 4; r++){
            int pr = p0 + lg*4 + r;
            if (pr < n)
                z4[(size_t)pr*256 + t*16 + l15] = f2bf(acc[t][r]);
        }
    }
}

// ---------- gather-max: streaming — cell's rows are contiguous in sorted z4 ----------
__global__ __launch_bounds__(256)
void k_gather(const unsigned* __restrict__ cnt, const unsigned* __restrict__ off,
              const unsigned short* __restrict__ z4,
              unsigned short* __restrict__ pooled){
    int lane = threadIdx.x & 63;
    int wid  = blockIdx.x*4 + (threadIdx.x >> 6);
    int wstride = gridDim.x * 4;
    for (int cell = wid; cell < NCELL; cell += wstride){
        unsigned cn = cnt[cell];
        unsigned o  = off[cell];
        float m0 = -__builtin_inff(), m1 = m0, m2 = m0, m3 = m0;
        for (unsigned p = 0; p < cn; p++){
            uint2 u = *(const uint2*)(z4 + (size_t)(o + p)*256 + lane*4);
            m0 = fmaxf(m0, __uint_as_float(u.x << 16));
            m1 = fmaxf(m1, __uint_as_float(u.x & 0xFFFF0000u));
            m2 = fmaxf(m2, __uint_as_float(u.y << 16));
            m3 = fmaxf(m3, __uint_as_float(u.y & 0xFFFF0000u));
        }
        if (cn == 0){ m0 = m1 = m2 = m3 = 0.f; }
        unsigned p0 = (__float_as_uint(m0) >> 16) | (__float_as_uint(m1) & 0xFFFF0000u);
        unsigned p1 = (__float_as_uint(m2) >> 16) | (__float_as_uint(m3) & 0xFFFF0000u);
        *(uint2*)(pooled + (size_t)cell*256 + lane*4) = make_uint2(p0, p1);
    }
}

// ---------- 3x3 maxpool: 4ch/thread uint2 loads, 4 y-subgroups (6-deep chains) ----------
// Phase 1: thread (c4=t&63 -> 4 channels, ysub=t>>6 -> 4 output rows each);
// 6 uint2 loads per y-step (512 B/wave/instr). Phase 2: c=t, float4 planar stores.
__global__ __launch_bounds__(256)
void k_maxpool(const unsigned short* __restrict__ pooled, float* __restrict__ out){
    __shared__ unsigned short tile[4*16*256];   // [g][yl][c] bf16 = 32 KB
    int t = threadIdx.x;
    int c4   = t & 63;                          // channels 4*c4 .. 4*c4+3
    int ysub = t >> 6;                          // 0..3: output rows [ysub*4, ysub*4+4)
    int gy0 = blockIdx.x * 16;
    int gx0 = blockIdx.y * 4;
    int b   = blockIdx.z;
    int ymax = GYd - gy0; if (ymax > 16) ymax = 16;
    const unsigned short* base = pooled + (size_t)b*GXY*256 + c4*4;

    float cA[4][4], cB[4][4];                   // [ch][g] rolling window
#pragma unroll
    for (int ch = 0; ch < 4; ch++)
#pragma unroll
        for (int g = 0; g < 4; g++){ cA[ch][g] = 0.f; cB[ch][g] = 0.f; }
    int yb = gy0 + ysub*4;
    for (int tt = 0; tt < 6; tt++){
        int yy = yb - 1 + tt;
        bool yok = (unsigned)yy < (unsigned)GYd;
        float v[4][6];
#pragma unroll
        for (int r = 0; r < 6; r++){
            int xx = gx0 - 1 + r;
            float u0 = -__builtin_inff(), u1 = u0, u2 = u0, u3 = u0;
            if (yok && (unsigned)xx < (unsigned)GXd){
                uint2 u = *(const uint2*)(base + ((size_t)xx*GYd + yy)*256);
                u0 = bf2f((unsigned short)(u.x & 0xFFFFu));
                u1 = bf2f((unsigned short)(u.x >> 16));
                u2 = bf2f((unsigned short)(u.y & 0xFFFFu));
                u3 = bf2f((unsigned short)(u.y >> 16));
            }
            v[0][r] = u0; v[1][r] = u1; v[2][r] = u2; v[3][r] = u3;
        }
        float cm[4][4];
#pragma unroll
        for (int ch = 0; ch < 4; ch++)
#pragma unroll
            for (int g = 0; g < 4; g++)
                cm[ch][g] = fmaxf(fmaxf(v[ch][g], v[ch][g+1]), v[ch][g+2]);
        if (tt >= 2){
            int yl = ysub*4 + tt - 2;
            if (yl < ymax){
#pragma unroll
                for (int g = 0; g < 4; g++){
                    unsigned lo = (unsigned)f2bf(fmaxf(fmaxf(cA[0][g], cB[0][g]), cm[0][g]))
                                | ((unsigned)f2bf(fmaxf(fmaxf(cA[1][g], cB[1][g]), cm[1][g])) << 16);
                    unsigned hi = (unsigned)f2bf(fmaxf(fmaxf(cA[2][g], cB[2][g]), cm[2][g]))
                                | ((unsigned)f2bf(fmaxf(fmaxf(cA[3][g], cB[3][g]), cm[3][g])) << 16);
                    *(uint2*)&tile[(g*16 + yl)*256 + c4*4] = make_uint2(lo, hi);
                }
            }
        }
#pragma unroll
        for (int ch = 0; ch < 4; ch++)
#pragma unroll
            for (int g = 0; g < 4; g++){ cA[ch][g] = cB[ch][g]; cB[ch][g] = cm[ch][g]; }
    }
    __syncthreads();

    int c = t;
#pragma unroll 1
    for (int g = 0; g < 4; g++){
        float* dst = out + ((size_t)b*258 + c)*GXY + (size_t)(gx0+g)*GYd + gy0;
        const unsigned short* srcl = &tile[g*16*256 + c];
#pragma unroll 1
        for (int y = 0; y < ymax; y += 4){
            float4 o4;
            o4.x = bf2f(srcl[(y+0)*256]);
            o4.y = bf2f(srcl[(y+1)*256]);
            o4.z = bf2f(srcl[(y+2)*256]);
            o4.w = bf2f(srcl[(y+3)*256]);
            *(float4*)(dst + y) = o4;
        }
    }
}

// ---------- residual channels ----------
__global__ __launch_bounds__(256)
void k_res(const unsigned* __restrict__ pres, float* __restrict__ out){
    int idx = blockIdx.x*256 + threadIdx.x;
    const int total = NBd*2*GXY;
    if (idx >= total) return;
    int gy = idx % GYd;
    int t  = idx / GYd;
    int gx = t % GXd;  t /= GXd;
    int r  = t & 1;
    int b  = t >> 1;
    unsigned u = pres[idx];
    float f = u ? unmapf(u) : 0.f;
    out[(((size_t)b*258 + 256 + r)*GXd + gx)*GYd + gy] = f;
}

extern "C" void kernel_launch(void* const* d_in, const int* in_sizes, int n_in,
                              void* d_out, int out_size, void* d_ws, size_t ws_size,
                              hipStream_t stream){
    (void)n_in; (void)out_size; (void)ws_size;
    const float* fea   = (const float*)d_in[0];
    const int*   ind   = (const int*)  d_in[1];
    const float* bn0_g = (const float*)d_in[2];
    const float* bn0_b = (const float*)d_in[3];
    const float* w1    = (const float*)d_in[4];
    const float* b1    = (const float*)d_in[5];
    const float* bn1_g = (const float*)d_in[6];
    const float* bn1_b = (const float*)d_in[7];
    const float* w2    = (const float*)d_in[8];
    const float* b2    = (const float*)d_in[9];
    const float* bn2_g = (const float*)d_in[10];
    const float* bn2_b = (const float*)d_in[11];
    const float* w3    = (const float*)d_in[12];
    const float* b3    = (const float*)d_in[13];
    const float* bn3_g = (const float*)d_in[14];
    const float* bn3_b = (const float*)d_in[15];
    const float* w4    = (const float*)d_in[16];
    const float* b4    = (const float*)d_in[17];

    int n = in_sizes[0] / 11;
    float invN = 1.0f / (float)n;

    // ---- ws layout ----
    const size_t Z4_B     = (size_t)240000*256*2;       // 122,880,000
    const size_t POOL_B   = (size_t)NCELL*256*2;        // 176,947,200
    const size_t PRES_B   = (size_t)NBd*2*GXY*4;        //   5,529,600
    const size_t CNT_B    = (size_t)NCELL*4;            //   2,764,800
    const size_t STAT_B   = 960*4;
    const size_t GCTR_B   = 256;

    char* base = (char*)d_ws;
    unsigned short* z4     = (unsigned short*)base;
    unsigned short* pooled = (unsigned short*)(base + Z4_B);
    // z1/z2/z3 alias the pooled region (dead before k_gather writes it)
    float*          z1     = (float*)(base + Z4_B);
    float*          z2     = (float*)(base + Z4_B + 30720000);
    unsigned short* z3     = (unsigned short*)(base + Z4_B + 92160000);
    unsigned* pres  = (unsigned*)(base + Z4_B + POOL_B);
    unsigned* cnt   = (unsigned*)((char*)pres + PRES_B);
    float*    stats = (float*)((char*)cnt + CNT_B);
    unsigned* gctr  = (unsigned*)((char*)stats + STAT_B);
    unsigned* off   = (unsigned*)((char*)gctr + GCTR_B);
    unsigned* list  = (unsigned*)((char*)off + CNT_B);
    unsigned* rank  = (unsigned*)((char*)list + (size_t)240000*4);

    float* sum0 = stats;       float* sq0 = stats + 16;
    float* sum1 = stats + 32;  float* sq1 = stats + 64;
    float* sum2 = stats + 96;  float* sq2 = stats + 160;
    float* sum3 = stats + 224; float* sq3 = stats + 352;
    float* a0 = stats + 480;   float* c0 = stats + 496;
    float* a1 = stats + 512;   float* c1 = stats + 544;
    float* a2 = stats + 576;   float* c2 = stats + 640;
    float* a3 = stats + 704;   float* c3 = stats + 832;

    hipMemsetAsync(pres, 0, PRES_B + CNT_B + STAT_B + GCTR_B, stream);

    int nb = (n + 255) / 256;
    int nb64 = (n + 63) / 64;
    k_stats0<<<nb, 256, 0, stream>>>(fea, sum0, sq0, n);
    k_fin<<<1, 128, 0, stream>>>(sum0, sq0, bn0_g, bn0_b, a0, c0, 9,  invN);
    k_l1<<<nb, 256, 0, stream>>>(fea, ind, w1, b1, a0, c0, z1, pres, cnt, rank, sum1, sq1, n);
    k_fin<<<1, 128, 0, stream>>>(sum1, sq1, bn1_g, bn1_b, a1, c1, 32, invN);
    k_l2<<<nb64, 256, 0, stream>>>(z1, w2, b2, a1, c1, z2, sum2, sq2, n);
    k_fin<<<1, 128, 0, stream>>>(sum2, sq2, bn2_g, bn2_b, a2, c2, 64, invN);
    k_l3<<<nb64, 256, 0, stream>>>(z2, w3, b3, a2, c2, z3, sum3, sq3, n);
    k_fin<<<1, 128, 0, stream>>>(sum3, sq3, bn3_g, bn3_b, a3, c3, 128, invN);

    k_off <<<(NCELL + 1023)/1024, 256, 0, stream>>>(cnt, off, gctr);
    k_fill<<<nb, 256, 0, stream>>>(ind, rank, off, list, n);

    k_l4<<<nb64, 256, 0, stream>>>(z3, list, w4, b4, a3, c3, z4, n);

    k_gather<<<2048, 256, 0, stream>>>(cnt, off, z4, pooled);

    k_maxpool<<<dim3(23, 120, 2), 256, 0, stream>>>(pooled, (float*)d_out);
    k_res<<<(NBd*2*GXY + 255) / 256, 256, 0, stream>>>(pres, (float*)d_out);
}